// Round 6
// baseline (5785.929 us; speedup 1.0000x reference)
//
#include <hip/hip_runtime.h>
#include <math.h>

#define BB 48
#define NN 96
#define EE 1024
#define DD 300
#define LL 4
#define G3 900          // 3*D
#define PP 150          // DD/2 packed f16 pairs
#define HDIM 3724       // D*(2L+1)+E
#define ROWS (BB*NN)    // 4608
#define NEGI -1.0e30f
#define KP300 304       // 300 padded to mult-of-8

typedef _Float16 half2_t __attribute__((ext_vector_type(2)));
typedef _Float16 h8 __attribute__((ext_vector_type(8)));
typedef float f4 __attribute__((ext_vector_type(4)));

__device__ __forceinline__ float sigm(float x){ return 1.0f/(1.0f+expf(-x)); }

// ---------------- transpose pwh (900,300) -> pwhT (300,900), fp32, scan-init only ----------------
__global__ void transpose_w(const float* __restrict__ gp_whh, float* __restrict__ wT)
{
    __shared__ float tile[32][33];
    int l = blockIdx.z;
    const float* src = gp_whh + (size_t)l*G3*DD;
    float* dst = wT + (size_t)l*DD*G3;
    int g0 = blockIdx.x*32;        // along 900
    int d0 = blockIdx.y*32;        // along 300
    int tx = threadIdx.x, ty = threadIdx.y;   // (32,8)
    #pragma unroll
    for (int r=0;r<32;r+=8){
        int g = g0+ty+r, d = d0+tx;
        tile[ty+r][tx] = (g<G3 && d<DD) ? src[(size_t)g*DD+d] : 0.f;
    }
    __syncthreads();
    #pragma unroll
    for (int r=0;r<32;r+=8){
        int d = d0+ty+r, g = g0+tx;
        if (d<DD && g<G3) dst[(size_t)d*G3+g] = tile[tx][ty+r];
    }
}

// ---------------- pack pwi (L,900,300) -> f16-pair layout (L,150,900) for scan ----------------
__global__ __launch_bounds__(256) void pack_pwi(const float* __restrict__ gp_wih,
                                                half2_t* __restrict__ pwiH)
{
    int l = blockIdx.y;
    int idx = blockIdx.x*256 + threadIdx.x;
    if (idx >= PP*G3) return;
    int p = idx / G3, g = idx % G3;
    const float* src = gp_wih + (size_t)l*G3*DD + (size_t)g*DD + 2*p;
    half2_t h;
    h.x = (_Float16)src[0];
    h.y = (_Float16)src[1];
    pwiH[(size_t)l*PP*G3 + idx] = h;
}

// ---------------- GRU weights [900][300] fp32 -> [900][304] f16 (zero-padded) ----------------
// z = l*3 + {0:pwh, 1:cwi, 2:cwh}
__global__ __launch_bounds__(256) void conv_gru_w(const float* __restrict__ gp_whh,
                                                  const float* __restrict__ gc_wih,
                                                  const float* __restrict__ gc_whh,
                                                  _Float16* __restrict__ outp)
{
    int z = blockIdx.y; int l = z/3, wsel = z%3;
    const float* src = (wsel==0?gp_whh:wsel==1?gc_wih:gc_whh) + (size_t)l*G3*DD;
    _Float16* dst = outp + (size_t)z*G3*KP300;
    int idx = blockIdx.x*256 + threadIdx.x;
    if (idx >= G3*KP300) return;
    int n = idx/KP300, k = idx%KP300;
    dst[idx] = (k<DD) ? (_Float16)src[(size_t)n*DD+k] : (_Float16)0.f;
}

// ---------------- transpose-convert [K][N] fp32 -> [N][Kpad] f16 ----------------
__global__ __launch_bounds__(256) void convT(const float* __restrict__ src,
                                             _Float16* __restrict__ dst,
                                             int K, int N, int Kpad)
{
    int idx = blockIdx.x*256 + threadIdx.x;
    if (idx >= N*Kpad) return;
    int n = idx/Kpad, k = idx%Kpad;
    dst[idx] = (k<K) ? (_Float16)src[(size_t)k*N + n] : (_Float16)0.f;
}

// ---------------- MFMA f16 GEMM: C(M x N) = act(A_f32 * B^T + bias) ----------------
__global__ __launch_bounds__(256) void gemm_mfma(
    const float* __restrict__ A, int lda,
    const _Float16* __restrict__ B, int Kpad,
    const float* __restrict__ bias,
    float* __restrict__ C, int ldc,
    int N, int K, int relu)
{
    constexpr int BM=128, BN=64, BK=32, KPS=40;
    __shared__ _Float16 As[BM][KPS];
    __shared__ _Float16 Bs[BN][KPS];
    int tid = threadIdx.x;
    int m0 = blockIdx.y*BM, n0 = blockIdx.x*BN;
    int w = tid>>6, lane = tid&63;
    int wy = w>>1, wx = w&1;
    int lm = lane&15, q = lane>>4;

    f4 acc[4][2];
    #pragma unroll
    for (int a=0;a<4;a++)
        #pragma unroll
        for (int b=0;b<2;b++)
            #pragma unroll
            for (int r=0;r<4;r++) acc[a][b][r]=0.f;

    int am = tid>>1, akg = (tid&1)*16;
    int bn = tid>>2, bkg = (tid&3)*8;
    const float* arow = A + (size_t)(m0+am)*lda;

    for (int k0=0; k0<K; k0+=BK){
        {
            __align__(16) _Float16 av[16];
            #pragma unroll
            for (int u=0;u<16;u+=4){
                int k = k0 + akg + u;
                float x0,x1,x2,x3;
                if (k+4 <= K){
                    float4 v = *(const float4*)(arow + k);
                    x0=v.x;x1=v.y;x2=v.z;x3=v.w;
                } else {
                    x0 = (k  <K)? arow[k  ]:0.f;
                    x1 = (k+1<K)? arow[k+1]:0.f;
                    x2 = (k+2<K)? arow[k+2]:0.f;
                    x3 = (k+3<K)? arow[k+3]:0.f;
                }
                av[u]=(_Float16)x0; av[u+1]=(_Float16)x1;
                av[u+2]=(_Float16)x2; av[u+3]=(_Float16)x3;
            }
            *(h8*)&As[am][akg]   = *(h8*)&av[0];
            *(h8*)&As[am][akg+8] = *(h8*)&av[8];
        }
        {
            int gk = k0 + bkg;
            h8 bv;
            #pragma unroll
            for (int j=0;j<8;j++) bv[j]=(_Float16)0.f;
            if (n0+bn < N && gk < Kpad)
                bv = *(const h8*)(B + (size_t)(n0+bn)*Kpad + gk);
            *(h8*)&Bs[bn][bkg] = bv;
        }
        __syncthreads();
        h8 af[4], bf[2];
        #pragma unroll
        for (int mb=0; mb<4; mb++) af[mb] = *(h8*)&As[wy*64+mb*16+lm][q*8];
        #pragma unroll
        for (int nb=0; nb<2; nb++) bf[nb] = *(h8*)&Bs[wx*32+nb*16+lm][q*8];
        #pragma unroll
        for (int mb=0; mb<4; mb++)
            #pragma unroll
            for (int nb=0; nb<2; nb++)
                acc[mb][nb] = __builtin_amdgcn_mfma_f32_16x16x32_f16(af[mb], bf[nb], acc[mb][nb], 0,0,0);
        __syncthreads();
    }
    #pragma unroll
    for (int mb=0; mb<4; mb++){
        int r0 = m0 + wy*64 + mb*16 + q*4;
        #pragma unroll
        for (int nb=0; nb<2; nb++){
            int c = n0 + wx*32 + nb*16 + lm;
            if (c < N){
                float bb = bias[c];
                #pragma unroll
                for (int reg=0; reg<4; reg++){
                    float v = acc[mb][nb][reg] + bb;
                    if (relu) v = fmaxf(v, 0.f);
                    C[(size_t)(r0+reg)*ldc + c] = v;
                }
            }
        }
    }
}

// ---------------- copy features into last 1024 cols of Hbuf ----------------
__global__ void featcopy(const float* __restrict__ f, float* __restrict__ H)
{
    size_t row = blockIdx.x;
    int t = threadIdx.x;
    float4 v = *(const float4*)(f + row*EE + t*4);
    *(float4*)(H + row*HDIM + 2700 + t*4) = v;
}

// ---------------- qdot[r] = Cin[r,:]·wq + gb ----------------
__global__ __launch_bounds__(256) void qdot_kernel(
    const float* __restrict__ Hbuf, int ccol,
    const float* __restrict__ wq, const float* __restrict__ gat_b, int l,
    float* __restrict__ qd)
{
    int row = blockIdx.x*4 + (threadIdx.x>>6);
    int lane = threadIdx.x & 63;
    const float* x = Hbuf + (size_t)row*HDIM + ccol;
    float s = 0.f;
    for (int d=lane; d<DD; d+=64) s += x[d]*wq[d];
    #pragma unroll
    for (int o=32;o>0;o>>=1) s += __shfl_down(s,o);
    if (lane==0) qd[row] = s + gat_b[l];
}

// ---------------- the sequential p-scan: one block per batch element ----------------
// Phase-D weights: EVEN k-pairs in registers (75 VGPRs, fits the 128-reg cap at
// 4 waves/SIMD — launch_bounds(1024,4) forces the 128 budget), ODD pairs stream from L2.
__global__ __launch_bounds__(1024, 4) void scan_kernel(
    float* __restrict__ Hbuf,
    const float* __restrict__ GHp,        // (4608,900) = Hin@pwh^T + pbh
    const half2_t* __restrict__ pwiH,     // (150,900) f16 pairs
    const float* __restrict__ pwhT,       // (300,900) fp32 (init only)
    const float* __restrict__ pbi,        // (900)
    const float* __restrict__ pbh,        // (900)
    const float* __restrict__ wk,         // (300)
    const float* __restrict__ qd,         // (4608), includes +gb
    const float* __restrict__ adj,        // (48,96,96)
    float* __restrict__ Mbuf,             // (4608,300)
    int ccol, int hcol, int pcol)
{
    int b = blockIdx.x;
    int t = threadIdx.x;

    __shared__ __align__(16) half2_t P_h2[NN][PP];   // 57600 B
    __shared__ __align__(16) float g_s[G3];
    __shared__ __align__(16) float Mpart[3][DD];
    __shared__ __align__(16) half2_t M_h2[PP];
    __shared__ __align__(16) float e_s[NN];
    __shared__ __align__(16) float pk_s[NN];
    __shared__ __align__(16) float pw_s[DD];
    __shared__ __align__(16) float adj_s[NN*NN];
    __shared__ __align__(16) float qd_s[NN];
    __shared__ __align__(16) float ghp_s[G3];
    __shared__ __align__(16) float hv_s[DD];

    size_t rowbase = (size_t)b*NN;

    // ---- one-time: even-pair weight column for gate t into registers (75 VGPRs)
    half2_t wreg[75];
    float pbi_r = 0.f;
    if (t < G3){
        pbi_r = pbi[t];
        const half2_t* W = pwiH + t;
        #pragma unroll
        for (int j=0;j<75;j++) wreg[j] = W[(size_t)(2*j)*G3];
    }
    float2 wk_r = make_float2(0.f,0.f);
    if (t < PP) wk_r = *(const float2*)&wk[2*t];

    for (int k=t; k<NN*NN; k+=1024) adj_s[k] = adj[rowbase*NN + k];
    if (t < NN) qd_s[t] = qd[rowbase + t];

    if (t < DD) Mpart[0][t] = Hbuf[rowbase*HDIM + ccol + t];   // Cin0
    __syncthreads();
    if (t < G3){
        float acc = pbh[t];
        #pragma unroll 4
        for (int d=0; d<DD; d++) acc += Mpart[0][d]*pwhT[(size_t)d*G3+t];
        g_s[t] = acc;
    }
    __syncthreads();
    if (t < PP){
        int d0 = 2*t, d1 = 2*t+1;
        float r0  = sigm(pbi[d0]      + g_s[d0]);
        float z0  = sigm(pbi[DD+d0]   + g_s[DD+d0]);
        float n0  = tanhf(pbi[2*DD+d0] + r0*g_s[2*DD+d0]);
        float p0  = (1.f-z0)*n0 + z0*Mpart[0][d0];
        float r1  = sigm(pbi[d1]      + g_s[d1]);
        float z1  = sigm(pbi[DD+d1]   + g_s[DD+d1]);
        float n1  = tanhf(pbi[2*DD+d1] + r1*g_s[2*DD+d1]);
        float p1  = (1.f-z1)*n1 + z1*Mpart[0][d1];
        *(float2*)&Hbuf[rowbase*HDIM + pcol + d0] = make_float2(p0,p1);
        half2_t ph; ph.x = (_Float16)p0; ph.y = (_Float16)p1;
        P_h2[0][t] = ph;
        pw_s[d0] = p0*wk_r.x;
        pw_s[d1] = p1*wk_r.y;
        *(float2*)&Mbuf[rowbase*DD + d0] = make_float2(0.f,0.f);
    }
    __syncthreads();

    for (int i=1;i<NN;i++){
        size_t row = rowbase + i;
        // ---- AB (wave 0): pk reduce + logits + softmax
        if (t < 64){
            float s = 0.f;
            for (int c=t;c<DD;c+=64) s += pw_s[c];
            #pragma unroll
            for (int o=32;o>0;o>>=1) s += __shfl_xor(s,o);
            if (t==0) pk_s[i-1] = s;
            float q = qd_s[i];
            float a0 = NEGI, a1 = NEGI;
            if (t < i){
                if (adj_s[i*NN+t] != 0.f) a0 = q + ((t==i-1)? s : pk_s[t]);
            }
            int j1 = 64+t;
            if (t < 32 && j1 < i){
                if (adj_s[i*NN+j1] != 0.f) a1 = q + ((j1==i-1)? s : pk_s[j1]);
            }
            float m = fmaxf(a0,a1);
            #pragma unroll
            for (int o=32;o>0;o>>=1) m = fmaxf(m, __shfl_xor(m,o));
            float e0 = expf(a0-m);
            float e1 = (t<32)? expf(a1-m) : 0.f;
            float ss = e0+e1;
            #pragma unroll
            for (int o=32;o>0;o>>=1) ss += __shfl_xor(ss,o);
            float inv = 1.f/ss;
            e_s[t] = e0*inv;
            if (t<32) e_s[64+t] = e1*inv;
        }
        __syncthreads();
        // ---- C (t<450): 3-way j-split weighted sum of LDS P rows; prefetchers (t>=512)
        if (t < 450){
            int g = t/150, dp = t%150;
            int cnt = (i+2)/3;
            int j0 = g*cnt; int j1 = j0+cnt; if (j1 > i) j1 = i;
            float m0=0.f, m1=0.f;
            for (int j=j0;j<j1;j++){
                float w = e_s[j];
                half2_t pv = P_h2[j][dp];
                m0 += w*(float)pv.x;
                m1 += w*(float)pv.y;
            }
            *(float2*)&Mpart[g][2*dp] = make_float2(m0,m1);
        } else if (t >= 512){
            int k = t-512;
            #pragma unroll
            for (int it=0; it<2; it++){
                int idx = k + it*512;
                if (idx < 450){
                    *(float2*)&ghp_s[2*idx] = *(const float2*)&GHp[row*G3 + 2*idx];
                } else if (idx < 600){
                    int h = idx-450;
                    *(float2*)&hv_s[2*h] = *(const float2*)&Hbuf[row*HDIM + hcol + 2*h];
                }
            }
        }
        __syncthreads();
        // ---- Csum (t<150): combine partials, write Mbuf + f16 M
        if (t < PP){
            float m0 = Mpart[0][2*t] + Mpart[1][2*t] + Mpart[2][2*t];
            float m1 = Mpart[0][2*t+1] + Mpart[1][2*t+1] + Mpart[2][2*t+1];
            half2_t mh; mh.x = (_Float16)m0; mh.y = (_Float16)m1;
            M_h2[t] = mh;
            *(float2*)&Mbuf[row*DD + 2*t] = make_float2(m0,m1);
        }
        __syncthreads();
        // ---- D (t<900): g = M @ pwi^T + pbi; even pairs from regs, odd pairs stream from L2
        if (t < G3){
            float acc0 = 0.f, acc1 = 0.f;
            const half2_t* Wodd = pwiH + G3 + t;      // pair index 1, step 2 -> (2j+1)
            #pragma unroll 4
            for (int c=0;c<37;c++){
                h8 mc = *(h8*)&M_h2[4*c];             // pairs 4c..4c+3, one b128 broadcast
                half2_t m0; m0.x=mc[0]; m0.y=mc[1];   // pair 4c   (even -> reg 2c)
                half2_t m1; m1.x=mc[2]; m1.y=mc[3];   // pair 4c+1 (odd  -> stream)
                half2_t m2; m2.x=mc[4]; m2.y=mc[5];   // pair 4c+2 (even -> reg 2c+1)
                half2_t m3; m3.x=mc[6]; m3.y=mc[7];   // pair 4c+3 (odd  -> stream)
                half2_t w1 = Wodd[(size_t)(4*c)*G3];
                half2_t w3 = Wodd[(size_t)(4*c+2)*G3];
                acc0 = __builtin_amdgcn_fdot2(wreg[2*c],   m0, acc0, false);
                acc1 = __builtin_amdgcn_fdot2(w1,          m1, acc1, false);
                acc0 = __builtin_amdgcn_fdot2(wreg[2*c+1], m2, acc0, false);
                acc1 = __builtin_amdgcn_fdot2(w3,          m3, acc1, false);
            }
            // tail: pairs 148 (even, reg 74) and 149 (odd, stream)
            acc0 = __builtin_amdgcn_fdot2(wreg[74], M_h2[148], acc0, false);
            acc1 = __builtin_amdgcn_fdot2(Wodd[(size_t)148*G3], M_h2[149], acc1, false);
            g_s[t] = pbi_r + acc0 + acc1;
        }
        __syncthreads();
        // ---- E (t<150): GRU combine (pure LDS), write P row + pw
        if (t < PP){
            int d0 = 2*t, d1 = 2*t+1;
            float2 hv = *(const float2*)&hv_s[d0];
            float r0  = sigm(g_s[d0]      + ghp_s[d0]);
            float z0  = sigm(g_s[DD+d0]   + ghp_s[DD+d0]);
            float n0  = tanhf(g_s[2*DD+d0] + r0*ghp_s[2*DD+d0]);
            float p0  = (1.f-z0)*n0 + z0*hv.x;
            float r1  = sigm(g_s[d1]      + ghp_s[d1]);
            float z1  = sigm(g_s[DD+d1]   + ghp_s[DD+d1]);
            float n1  = tanhf(g_s[2*DD+d1] + r1*ghp_s[2*DD+d1]);
            float p1  = (1.f-z1)*n1 + z1*hv.y;
            *(float2*)&Hbuf[row*HDIM + pcol + d0] = make_float2(p0,p1);
            half2_t ph; ph.x = (_Float16)p0; ph.y = (_Float16)p1;
            P_h2[i][t] = ph;
            pw_s[d0] = p0*wk_r.x;
            pw_s[d1] = p1*wk_r.y;
        }
        __syncthreads();
    }
}

// ---------------- c-side elementwise combine ----------------
__global__ __launch_bounds__(320) void combine_c(
    const float* __restrict__ GIc, const float* __restrict__ GHc,
    const float* __restrict__ Mbuf, float* __restrict__ Hbuf, int clcol)
{
    size_t row = blockIdx.x;
    int d = threadIdx.x;
    if (d < DD){
        float ir = GIc[row*G3+d], iz = GIc[row*G3+DD+d], inn = GIc[row*G3+2*DD+d];
        float hr = GHc[row*G3+d], hz = GHc[row*G3+DD+d], hn  = GHc[row*G3+2*DD+d];
        float r  = sigm(ir+hr);
        float z  = sigm(iz+hz);
        float nn = tanhf(inn + r*hn);
        float h  = Mbuf[row*DD+d];
        Hbuf[row*HDIM + clcol + d] = (1.f-z)*nn + z*h;
    }
}

// ---------------- logits: out = x2 @ w2 + b2 (N=7) ----------------
__global__ __launch_bounds__(64) void logits_kernel(
    const float* __restrict__ x2, const float* __restrict__ w2,
    const float* __restrict__ b2, float* __restrict__ out)
{
    size_t row = blockIdx.x;
    int lane = threadIdx.x;
    float acc[7]={0,0,0,0,0,0,0};
    for (int d=lane; d<DD; d+=64){
        float x = x2[row*DD+d];
        #pragma unroll
        for (int c=0;c<7;c++) acc[c] += x*w2[d*7+c];
    }
    #pragma unroll
    for (int c=0;c<7;c++){
        float s = acc[c];
        #pragma unroll
        for (int o=32;o>0;o>>=1) s += __shfl_down(s,o);
        if (lane==0) out[row*7+c] = s + b2[c];
    }
}

extern "C" void kernel_launch(void* const* d_in, const int* in_sizes, int n_in,
                              void* d_out, int out_size, void* d_ws, size_t ws_size,
                              hipStream_t stream)
{
    const float* features = (const float*)d_in[0];
    const float* adj      = (const float*)d_in[1];
    const float* fc1_w    = (const float*)d_in[3];
    const float* fc1_b    = (const float*)d_in[4];
    const float* gc_wih   = (const float*)d_in[5];
    const float* gc_whh   = (const float*)d_in[6];
    const float* gc_bih   = (const float*)d_in[7];
    const float* gc_bhh   = (const float*)d_in[8];
    const float* gp_wih   = (const float*)d_in[9];
    const float* gp_whh   = (const float*)d_in[10];
    const float* gp_bih   = (const float*)d_in[11];
    const float* gp_bhh   = (const float*)d_in[12];
    const float* gat_wq   = (const float*)d_in[13];
    const float* gat_wk   = (const float*)d_in[14];
    const float* gat_b    = (const float*)d_in[15];
    const float* mlp_w0   = (const float*)d_in[16];
    const float* mlp_b0   = (const float*)d_in[17];
    const float* mlp_w1   = (const float*)d_in[18];
    const float* mlp_b1   = (const float*)d_in[19];
    const float* mlp_w2   = (const float*)d_in[20];
    const float* mlp_b2   = (const float*)d_in[21];
    float* out = (float*)d_out;

    float* ws = (float*)d_ws;
    size_t off = 0;
    float* Hbuf = ws + off; off += (size_t)ROWS*HDIM;
    float* bufA = ws + off; off += (size_t)ROWS*G3;    // GHp
    float* bufB = ws + off; off += (size_t)ROWS*G3;    // GIc / x1
    float* bufC = ws + off; off += (size_t)ROWS*G3;    // GHc / x2
    float* Mbuf = ws + off; off += (size_t)ROWS*DD;
    float* qd   = ws + off; off += ROWS;
    float* wT   = ws + off; off += (size_t)LL*DD*G3;               // pwhT fp32 (scan init)
    half2_t* pwiH = (half2_t*)(ws + off); off += (size_t)LL*PP*G3; // scan weights
    _Float16* gruF = (_Float16*)(ws + off); off += (size_t)12*G3*KP300/2;  // 12x [900][304] f16
    _Float16* fc1F = (_Float16*)(ws + off); off += (size_t)DD*EE/2;        // [300][1024]
    _Float16* mlp0F= (_Float16*)(ws + off); off += (size_t)DD*3728/2;      // [300][3728]
    _Float16* mlp1F= (_Float16*)(ws + off); off += (size_t)DD*KP300/2;     // [300][304]
    (void)ws_size; (void)in_sizes; (void)n_in; (void)out_size;

    // 1. weight prep
    {
        dim3 g((G3+31)/32, (DD+31)/32, LL);
        dim3 bl(32,8);
        transpose_w<<<g, bl, 0, stream>>>(gp_whh, wT);
        pack_pwi<<<dim3((PP*G3+255)/256, LL), 256, 0, stream>>>(gp_wih, pwiH);
        conv_gru_w<<<dim3((G3*KP300+255)/256, 12), 256, 0, stream>>>(gp_whh, gc_wih, gc_whh, gruF);
        convT<<<(DD*EE+255)/256, 256, 0, stream>>>(fc1_w, fc1F, EE, DD, EE);
        convT<<<(DD*3728+255)/256, 256, 0, stream>>>(mlp_w0, mlp0F, HDIM, DD, 3728);
        convT<<<(DD*KP300+255)/256, 256, 0, stream>>>(mlp_w1, mlp1F, DD, DD, KP300);
    }
    // 2. H0 = relu(features @ fc1_w + fc1_b) -> Hbuf col 0
    gemm_mfma<<<dim3(5,36),256,0,stream>>>(features, EE, fc1F, EE, fc1_b,
                                           Hbuf, HDIM, DD, EE, 1);
    // 3. features -> Hbuf cols [2700,3724)
    featcopy<<<ROWS,256,0,stream>>>(features, Hbuf);

    for (int l=0;l<LL;l++){
        int ccol  = (l==0)? 0 : 300 + (l-1)*600;
        int hcol  = l*300;
        int pcol  = 600 + l*600;
        int clcol = 300 + l*600;
        const float* pwhT = wT + (size_t)l*DD*G3;
        const half2_t* pwiHl = pwiH + (size_t)l*PP*G3;
        const _Float16* pwhF = gruF + (size_t)(l*3+0)*G3*KP300;
        const _Float16* cwiF = gruF + (size_t)(l*3+1)*G3*KP300;
        const _Float16* cwhF = gruF + (size_t)(l*3+2)*G3*KP300;

        // GHp = Hin @ pwh^T + pbh
        gemm_mfma<<<dim3(15,36),256,0,stream>>>(Hbuf+hcol, HDIM, pwhF, KP300,
                                                gp_bhh + l*G3, bufA, G3, G3, DD, 0);
        // qdot = Cin·wq + gb
        qdot_kernel<<<1152,256,0,stream>>>(Hbuf, ccol, gat_wq + l*DD, gat_b, l, qd);
        // sequential p-scan
        scan_kernel<<<BB,1024,0,stream>>>(Hbuf, bufA, pwiHl, pwhT,
                                          gp_bih + l*G3, gp_bhh + l*G3,
                                          gat_wk + l*DD, qd, adj, Mbuf,
                                          ccol, hcol, pcol);
        // GIc = Cin @ cwi^T + cbi
        gemm_mfma<<<dim3(15,36),256,0,stream>>>(Hbuf+ccol, HDIM, cwiF, KP300,
                                                gc_bih + l*G3, bufB, G3, G3, DD, 0);
        // GHc = M @ cwh^T + cbh
        gemm_mfma<<<dim3(15,36),256,0,stream>>>(Mbuf, DD, cwhF, KP300,
                                                gc_bhh + l*G3, bufC, G3, G3, DD, 0);
        // CL = GRU-combine
        combine_c<<<ROWS,320,0,stream>>>(bufB, bufC, Mbuf, Hbuf, clcol);
    }

    // MLP
    gemm_mfma<<<dim3(5,36),256,0,stream>>>(Hbuf, HDIM, mlp0F, 3728, mlp_b0,
                                           bufB, DD, DD, HDIM, 1);
    gemm_mfma<<<dim3(5,36),256,0,stream>>>(bufB, DD, mlp1F, KP300, mlp_b1,
                                           bufC, DD, DD, DD, 1);
    logits_kernel<<<ROWS,64,0,stream>>>(bufC, mlp_w2, mlp_b2, out);
}

// Round 7
// 3876.387 us; speedup vs baseline: 1.4926x; 1.4926x over previous
//
#include <hip/hip_runtime.h>
#include <math.h>

#define BB 48
#define NN 96
#define EE 1024
#define DD 300
#define LL 4
#define G3 900          // 3*D
#define PP 150          // DD/2 packed f16 pairs
#define HDIM 3724       // D*(2L+1)+E
#define ROWS (BB*NN)    // 4608
#define NEGI -1.0e30f
#define KP300 304       // 300 padded to mult-of-8

typedef _Float16 half2_t __attribute__((ext_vector_type(2)));
typedef _Float16 h8 __attribute__((ext_vector_type(8)));
typedef float f4 __attribute__((ext_vector_type(4)));

__device__ __forceinline__ float sigm(float x){ return 1.0f/(1.0f+expf(-x)); }

// ---------------- transpose pwh (900,300) -> pwhT (300,900), fp32, scan-init only ----------------
__global__ void transpose_w(const float* __restrict__ gp_whh, float* __restrict__ wT)
{
    __shared__ float tile[32][33];
    int l = blockIdx.z;
    const float* src = gp_whh + (size_t)l*G3*DD;
    float* dst = wT + (size_t)l*DD*G3;
    int g0 = blockIdx.x*32;        // along 900
    int d0 = blockIdx.y*32;        // along 300
    int tx = threadIdx.x, ty = threadIdx.y;   // (32,8)
    #pragma unroll
    for (int r=0;r<32;r+=8){
        int g = g0+ty+r, d = d0+tx;
        tile[ty+r][tx] = (g<G3 && d<DD) ? src[(size_t)g*DD+d] : 0.f;
    }
    __syncthreads();
    #pragma unroll
    for (int r=0;r<32;r+=8){
        int d = d0+ty+r, g = g0+tx;
        if (d<DD && g<G3) dst[(size_t)d*G3+g] = tile[tx][ty+r];
    }
}

// ---------------- pack pwi (L,900,300) -> f16-pair layout (L,150,900) for scan ----------------
__global__ __launch_bounds__(256) void pack_pwi(const float* __restrict__ gp_wih,
                                                half2_t* __restrict__ pwiH)
{
    int l = blockIdx.y;
    int idx = blockIdx.x*256 + threadIdx.x;
    if (idx >= PP*G3) return;
    int p = idx / G3, g = idx % G3;
    const float* src = gp_wih + (size_t)l*G3*DD + (size_t)g*DD + 2*p;
    half2_t h;
    h.x = (_Float16)src[0];
    h.y = (_Float16)src[1];
    pwiH[(size_t)l*PP*G3 + idx] = h;
}

// ---------------- GRU weights [900][300] fp32 -> [900][304] f16 (zero-padded) ----------------
// z = l*3 + {0:pwh, 1:cwi, 2:cwh}
__global__ __launch_bounds__(256) void conv_gru_w(const float* __restrict__ gp_whh,
                                                  const float* __restrict__ gc_wih,
                                                  const float* __restrict__ gc_whh,
                                                  _Float16* __restrict__ outp)
{
    int z = blockIdx.y; int l = z/3, wsel = z%3;
    const float* src = (wsel==0?gp_whh:wsel==1?gc_wih:gc_whh) + (size_t)l*G3*DD;
    _Float16* dst = outp + (size_t)z*G3*KP300;
    int idx = blockIdx.x*256 + threadIdx.x;
    if (idx >= G3*KP300) return;
    int n = idx/KP300, k = idx%KP300;
    dst[idx] = (k<DD) ? (_Float16)src[(size_t)n*DD+k] : (_Float16)0.f;
}

// ---------------- transpose-convert [K][N] fp32 -> [N][Kpad] f16 ----------------
__global__ __launch_bounds__(256) void convT(const float* __restrict__ src,
                                             _Float16* __restrict__ dst,
                                             int K, int N, int Kpad)
{
    int idx = blockIdx.x*256 + threadIdx.x;
    if (idx >= N*Kpad) return;
    int n = idx/Kpad, k = idx%Kpad;
    dst[idx] = (k<K) ? (_Float16)src[(size_t)k*N + n] : (_Float16)0.f;
}

// ---------------- MFMA f16 GEMM: C(M x N) = act(A_f32 * B^T + bias) ----------------
__global__ __launch_bounds__(256) void gemm_mfma(
    const float* __restrict__ A, int lda,
    const _Float16* __restrict__ B, int Kpad,
    const float* __restrict__ bias,
    float* __restrict__ C, int ldc,
    int N, int K, int relu)
{
    constexpr int BM=128, BN=64, BK=32, KPS=40;
    __shared__ _Float16 As[BM][KPS];
    __shared__ _Float16 Bs[BN][KPS];
    int tid = threadIdx.x;
    int m0 = blockIdx.y*BM, n0 = blockIdx.x*BN;
    int w = tid>>6, lane = tid&63;
    int wy = w>>1, wx = w&1;
    int lm = lane&15, q = lane>>4;

    f4 acc[4][2];
    #pragma unroll
    for (int a=0;a<4;a++)
        #pragma unroll
        for (int b=0;b<2;b++)
            #pragma unroll
            for (int r=0;r<4;r++) acc[a][b][r]=0.f;

    int am = tid>>1, akg = (tid&1)*16;
    int bn = tid>>2, bkg = (tid&3)*8;
    const float* arow = A + (size_t)(m0+am)*lda;

    for (int k0=0; k0<K; k0+=BK){
        {
            __align__(16) _Float16 av[16];
            #pragma unroll
            for (int u=0;u<16;u+=4){
                int k = k0 + akg + u;
                float x0,x1,x2,x3;
                if (k+4 <= K){
                    float4 v = *(const float4*)(arow + k);
                    x0=v.x;x1=v.y;x2=v.z;x3=v.w;
                } else {
                    x0 = (k  <K)? arow[k  ]:0.f;
                    x1 = (k+1<K)? arow[k+1]:0.f;
                    x2 = (k+2<K)? arow[k+2]:0.f;
                    x3 = (k+3<K)? arow[k+3]:0.f;
                }
                av[u]=(_Float16)x0; av[u+1]=(_Float16)x1;
                av[u+2]=(_Float16)x2; av[u+3]=(_Float16)x3;
            }
            *(h8*)&As[am][akg]   = *(h8*)&av[0];
            *(h8*)&As[am][akg+8] = *(h8*)&av[8];
        }
        {
            int gk = k0 + bkg;
            h8 bv;
            #pragma unroll
            for (int j=0;j<8;j++) bv[j]=(_Float16)0.f;
            if (n0+bn < N && gk < Kpad)
                bv = *(const h8*)(B + (size_t)(n0+bn)*Kpad + gk);
            *(h8*)&Bs[bn][bkg] = bv;
        }
        __syncthreads();
        h8 af[4], bf[2];
        #pragma unroll
        for (int mb=0; mb<4; mb++) af[mb] = *(h8*)&As[wy*64+mb*16+lm][q*8];
        #pragma unroll
        for (int nb=0; nb<2; nb++) bf[nb] = *(h8*)&Bs[wx*32+nb*16+lm][q*8];
        #pragma unroll
        for (int mb=0; mb<4; mb++)
            #pragma unroll
            for (int nb=0; nb<2; nb++)
                acc[mb][nb] = __builtin_amdgcn_mfma_f32_16x16x32_f16(af[mb], bf[nb], acc[mb][nb], 0,0,0);
        __syncthreads();
    }
    #pragma unroll
    for (int mb=0; mb<4; mb++){
        int r0 = m0 + wy*64 + mb*16 + q*4;
        #pragma unroll
        for (int nb=0; nb<2; nb++){
            int c = n0 + wx*32 + nb*16 + lm;
            if (c < N){
                float bb = bias[c];
                #pragma unroll
                for (int reg=0; reg<4; reg++){
                    float v = acc[mb][nb][reg] + bb;
                    if (relu) v = fmaxf(v, 0.f);
                    C[(size_t)(r0+reg)*ldc + c] = v;
                }
            }
        }
    }
}

// ---------------- copy features into last 1024 cols of Hbuf ----------------
__global__ void featcopy(const float* __restrict__ f, float* __restrict__ H)
{
    size_t row = blockIdx.x;
    int t = threadIdx.x;
    float4 v = *(const float4*)(f + row*EE + t*4);
    *(float4*)(H + row*HDIM + 2700 + t*4) = v;
}

// ---------------- qdot[r] = Cin[r,:]·wq + gb ----------------
__global__ __launch_bounds__(256) void qdot_kernel(
    const float* __restrict__ Hbuf, int ccol,
    const float* __restrict__ wq, const float* __restrict__ gat_b, int l,
    float* __restrict__ qd)
{
    int row = blockIdx.x*4 + (threadIdx.x>>6);
    int lane = threadIdx.x & 63;
    const float* x = Hbuf + (size_t)row*HDIM + ccol;
    float s = 0.f;
    for (int d=lane; d<DD; d+=64) s += x[d]*wq[d];
    #pragma unroll
    for (int o=32;o>0;o>>=1) s += __shfl_down(s,o);
    if (lane==0) qd[row] = s + gat_b[l];
}

// ---------------- the sequential p-scan: one block per batch element ----------------
// Phase D: pure L2 weight stream (no register residency — spills twice-confirmed),
// 4 independent load+dot streams, M via h8 same-address LDS broadcasts.
__global__ __launch_bounds__(1024) void scan_kernel(
    float* __restrict__ Hbuf,
    const float* __restrict__ GHp,        // (4608,900) = Hin@pwh^T + pbh
    const half2_t* __restrict__ pwiH,     // (150,900) f16 pairs
    const float* __restrict__ pwhT,       // (300,900) fp32 (init only)
    const float* __restrict__ pbi,        // (900)
    const float* __restrict__ pbh,        // (900)
    const float* __restrict__ wk,         // (300)
    const float* __restrict__ qd,         // (4608), includes +gb
    const float* __restrict__ adj,        // (48,96,96)
    float* __restrict__ Mbuf,             // (4608,300)
    int ccol, int hcol, int pcol)
{
    int b = blockIdx.x;
    int t = threadIdx.x;

    __shared__ __align__(16) half2_t P_h2[NN][PP];   // 57600 B
    __shared__ __align__(16) float g_s[G3];
    __shared__ __align__(16) float Mpart[3][DD];
    __shared__ __align__(16) half2_t M_h2[PP];
    __shared__ __align__(16) float e_s[NN];
    __shared__ __align__(16) float pk_s[NN];
    __shared__ __align__(16) float pw_s[DD];
    __shared__ __align__(16) float adj_s[NN*NN];
    __shared__ __align__(16) float qd_s[NN];
    __shared__ __align__(16) float ghp_s[G3];
    __shared__ __align__(16) float hv_s[DD];

    size_t rowbase = (size_t)b*NN;

    for (int k=t; k<NN*NN; k+=1024) adj_s[k] = adj[rowbase*NN + k];
    if (t < NN) qd_s[t] = qd[rowbase + t];

    if (t < DD) Mpart[0][t] = Hbuf[rowbase*HDIM + ccol + t];   // Cin0
    __syncthreads();
    if (t < G3){
        float acc = pbh[t];
        #pragma unroll 4
        for (int d=0; d<DD; d++) acc += Mpart[0][d]*pwhT[(size_t)d*G3+t];
        g_s[t] = acc;
    }
    __syncthreads();
    if (t < PP){
        int d0 = 2*t, d1 = 2*t+1;
        float r0  = sigm(pbi[d0]      + g_s[d0]);
        float z0  = sigm(pbi[DD+d0]   + g_s[DD+d0]);
        float n0  = tanhf(pbi[2*DD+d0] + r0*g_s[2*DD+d0]);
        float p0  = (1.f-z0)*n0 + z0*Mpart[0][d0];
        float r1  = sigm(pbi[d1]      + g_s[d1]);
        float z1  = sigm(pbi[DD+d1]   + g_s[DD+d1]);
        float n1  = tanhf(pbi[2*DD+d1] + r1*g_s[2*DD+d1]);
        float p1  = (1.f-z1)*n1 + z1*Mpart[0][d1];
        *(float2*)&Hbuf[rowbase*HDIM + pcol + d0] = make_float2(p0,p1);
        half2_t ph; ph.x = (_Float16)p0; ph.y = (_Float16)p1;
        P_h2[0][t] = ph;
        pw_s[d0] = p0*wk[d0];
        pw_s[d1] = p1*wk[d1];
        *(float2*)&Mbuf[rowbase*DD + d0] = make_float2(0.f,0.f);
    }
    __syncthreads();

    for (int i=1;i<NN;i++){
        size_t row = rowbase + i;
        // ---- AB (wave 0): pk reduce + logits + softmax
        if (t < 64){
            float s = 0.f;
            for (int c=t;c<DD;c+=64) s += pw_s[c];
            #pragma unroll
            for (int o=32;o>0;o>>=1) s += __shfl_xor(s,o);
            if (t==0) pk_s[i-1] = s;
            float q = qd_s[i];
            float a0 = NEGI, a1 = NEGI;
            if (t < i){
                if (adj_s[i*NN+t] != 0.f) a0 = q + ((t==i-1)? s : pk_s[t]);
            }
            int j1 = 64+t;
            if (t < 32 && j1 < i){
                if (adj_s[i*NN+j1] != 0.f) a1 = q + ((j1==i-1)? s : pk_s[j1]);
            }
            float m = fmaxf(a0,a1);
            #pragma unroll
            for (int o=32;o>0;o>>=1) m = fmaxf(m, __shfl_xor(m,o));
            float e0 = expf(a0-m);
            float e1 = (t<32)? expf(a1-m) : 0.f;
            float ss = e0+e1;
            #pragma unroll
            for (int o=32;o>0;o>>=1) ss += __shfl_xor(ss,o);
            float inv = 1.f/ss;
            e_s[t] = e0*inv;
            if (t<32) e_s[64+t] = e1*inv;
        }
        __syncthreads();
        // ---- C (t<450): 3-way j-split weighted sum of LDS P rows; prefetchers (t>=512)
        if (t < 450){
            int g = t/150, dp = t%150;
            int cnt = (i+2)/3;
            int j0 = g*cnt; int j1 = j0+cnt; if (j1 > i) j1 = i;
            float m0=0.f, m1=0.f;
            for (int j=j0;j<j1;j++){
                float w = e_s[j];
                half2_t pv = P_h2[j][dp];
                m0 += w*(float)pv.x;
                m1 += w*(float)pv.y;
            }
            *(float2*)&Mpart[g][2*dp] = make_float2(m0,m1);
        } else if (t >= 512){
            int k = t-512;
            #pragma unroll
            for (int it=0; it<2; it++){
                int idx = k + it*512;
                if (idx < 450){
                    *(float2*)&ghp_s[2*idx] = *(const float2*)&GHp[row*G3 + 2*idx];
                } else if (idx < 600){
                    int h = idx-450;
                    *(float2*)&hv_s[2*h] = *(const float2*)&Hbuf[row*HDIM + hcol + 2*h];
                }
            }
        }
        __syncthreads();
        // ---- Csum (t<150): combine partials, write Mbuf + f16 M
        if (t < PP){
            float m0 = Mpart[0][2*t] + Mpart[1][2*t] + Mpart[2][2*t];
            float m1 = Mpart[0][2*t+1] + Mpart[1][2*t+1] + Mpart[2][2*t+1];
            half2_t mh; mh.x = (_Float16)m0; mh.y = (_Float16)m1;
            M_h2[t] = mh;
            *(float2*)&Mbuf[row*DD + 2*t] = make_float2(m0,m1);
        }
        __syncthreads();
        // ---- D (t<900): g = M @ pwi^T + pbi; 4 L2 streams + h8 M broadcasts
        if (t < G3){
            const half2_t* W = pwiH + t;
            float a0=0.f, a1=0.f, a2=0.f, a3=0.f;
            #pragma unroll 8
            for (int c=0;c<37;c++){
                h8 mc = *(h8*)&M_h2[4*c];           // pairs 4c..4c+3, one b128 broadcast
                half2_t m0; m0.x=mc[0]; m0.y=mc[1];
                half2_t m1; m1.x=mc[2]; m1.y=mc[3];
                half2_t m2; m2.x=mc[4]; m2.y=mc[5];
                half2_t m3; m3.x=mc[6]; m3.y=mc[7];
                half2_t w0 = W[(size_t)(4*c  )*G3];
                half2_t w1 = W[(size_t)(4*c+1)*G3];
                half2_t w2 = W[(size_t)(4*c+2)*G3];
                half2_t w3 = W[(size_t)(4*c+3)*G3];
                a0 = __builtin_amdgcn_fdot2(w0, m0, a0, false);
                a1 = __builtin_amdgcn_fdot2(w1, m1, a1, false);
                a2 = __builtin_amdgcn_fdot2(w2, m2, a2, false);
                a3 = __builtin_amdgcn_fdot2(w3, m3, a3, false);
            }
            // tail: pairs 148,149
            a0 = __builtin_amdgcn_fdot2(W[(size_t)148*G3], M_h2[148], a0, false);
            a1 = __builtin_amdgcn_fdot2(W[(size_t)149*G3], M_h2[149], a1, false);
            g_s[t] = pbi[t] + (a0+a2) + (a1+a3);
        }
        __syncthreads();
        // ---- E (t<150): GRU combine (pure LDS), write P row + pw
        if (t < PP){
            int d0 = 2*t, d1 = 2*t+1;
            float2 hv = *(const float2*)&hv_s[d0];
            float2 wk2 = *(const float2*)&wk[d0];
            float r0  = sigm(g_s[d0]      + ghp_s[d0]);
            float z0  = sigm(g_s[DD+d0]   + ghp_s[DD+d0]);
            float n0  = tanhf(g_s[2*DD+d0] + r0*ghp_s[2*DD+d0]);
            float p0  = (1.f-z0)*n0 + z0*hv.x;
            float r1  = sigm(g_s[d1]      + ghp_s[d1]);
            float z1  = sigm(g_s[DD+d1]   + ghp_s[DD+d1]);
            float n1  = tanhf(g_s[2*DD+d1] + r1*ghp_s[2*DD+d1]);
            float p1  = (1.f-z1)*n1 + z1*hv.y;
            *(float2*)&Hbuf[row*HDIM + pcol + d0] = make_float2(p0,p1);
            half2_t ph; ph.x = (_Float16)p0; ph.y = (_Float16)p1;
            P_h2[i][t] = ph;
            pw_s[d0] = p0*wk2.x;
            pw_s[d1] = p1*wk2.y;
        }
        __syncthreads();
    }
}

// ---------------- c-side elementwise combine ----------------
__global__ __launch_bounds__(320) void combine_c(
    const float* __restrict__ GIc, const float* __restrict__ GHc,
    const float* __restrict__ Mbuf, float* __restrict__ Hbuf, int clcol)
{
    size_t row = blockIdx.x;
    int d = threadIdx.x;
    if (d < DD){
        float ir = GIc[row*G3+d], iz = GIc[row*G3+DD+d], inn = GIc[row*G3+2*DD+d];
        float hr = GHc[row*G3+d], hz = GHc[row*G3+DD+d], hn  = GHc[row*G3+2*DD+d];
        float r  = sigm(ir+hr);
        float z  = sigm(iz+hz);
        float nn = tanhf(inn + r*hn);
        float h  = Mbuf[row*DD+d];
        Hbuf[row*HDIM + clcol + d] = (1.f-z)*nn + z*h;
    }
}

// ---------------- logits: out = x2 @ w2 + b2 (N=7) ----------------
__global__ __launch_bounds__(64) void logits_kernel(
    const float* __restrict__ x2, const float* __restrict__ w2,
    const float* __restrict__ b2, float* __restrict__ out)
{
    size_t row = blockIdx.x;
    int lane = threadIdx.x;
    float acc[7]={0,0,0,0,0,0,0};
    for (int d=lane; d<DD; d+=64){
        float x = x2[row*DD+d];
        #pragma unroll
        for (int c=0;c<7;c++) acc[c] += x*w2[d*7+c];
    }
    #pragma unroll
    for (int c=0;c<7;c++){
        float s = acc[c];
        #pragma unroll
        for (int o=32;o>0;o>>=1) s += __shfl_down(s,o);
        if (lane==0) out[row*7+c] = s + b2[c];
    }
}

extern "C" void kernel_launch(void* const* d_in, const int* in_sizes, int n_in,
                              void* d_out, int out_size, void* d_ws, size_t ws_size,
                              hipStream_t stream)
{
    const float* features = (const float*)d_in[0];
    const float* adj      = (const float*)d_in[1];
    const float* fc1_w    = (const float*)d_in[3];
    const float* fc1_b    = (const float*)d_in[4];
    const float* gc_wih   = (const float*)d_in[5];
    const float* gc_whh   = (const float*)d_in[6];
    const float* gc_bih   = (const float*)d_in[7];
    const float* gc_bhh   = (const float*)d_in[8];
    const float* gp_wih   = (const float*)d_in[9];
    const float* gp_whh   = (const float*)d_in[10];
    const float* gp_bih   = (const float*)d_in[11];
    const float* gp_bhh   = (const float*)d_in[12];
    const float* gat_wq   = (const float*)d_in[13];
    const float* gat_wk   = (const float*)d_in[14];
    const float* gat_b    = (const float*)d_in[15];
    const float* mlp_w0   = (const float*)d_in[16];
    const float* mlp_b0   = (const float*)d_in[17];
    const float* mlp_w1   = (const float*)d_in[18];
    const float* mlp_b1   = (const float*)d_in[19];
    const float* mlp_w2   = (const float*)d_in[20];
    const float* mlp_b2   = (const float*)d_in[21];
    float* out = (float*)d_out;

    float* ws = (float*)d_ws;
    size_t off = 0;
    float* Hbuf = ws + off; off += (size_t)ROWS*HDIM;
    float* bufA = ws + off; off += (size_t)ROWS*G3;    // GHp
    float* bufB = ws + off; off += (size_t)ROWS*G3;    // GIc / x1
    float* bufC = ws + off; off += (size_t)ROWS*G3;    // GHc / x2
    float* Mbuf = ws + off; off += (size_t)ROWS*DD;
    float* qd   = ws + off; off += ROWS;
    float* wT   = ws + off; off += (size_t)LL*DD*G3;               // pwhT fp32 (scan init)
    half2_t* pwiH = (half2_t*)(ws + off); off += (size_t)LL*PP*G3; // scan weights
    _Float16* gruF = (_Float16*)(ws + off); off += (size_t)12*G3*KP300/2;  // 12x [900][304] f16
    _Float16* fc1F = (_Float16*)(ws + off); off += (size_t)DD*EE/2;        // [300][1024]
    _Float16* mlp0F= (_Float16*)(ws + off); off += (size_t)DD*3728/2;      // [300][3728]
    _Float16* mlp1F= (_Float16*)(ws + off); off += (size_t)DD*KP300/2;     // [300][304]
    (void)ws_size; (void)in_sizes; (void)n_in; (void)out_size;

    // 1. weight prep
    {
        dim3 g((G3+31)/32, (DD+31)/32, LL);
        dim3 bl(32,8);
        transpose_w<<<g, bl, 0, stream>>>(gp_whh, wT);
        pack_pwi<<<dim3((PP*G3+255)/256, LL), 256, 0, stream>>>(gp_wih, pwiH);
        conv_gru_w<<<dim3((G3*KP300+255)/256, 12), 256, 0, stream>>>(gp_whh, gc_wih, gc_whh, gruF);
        convT<<<(DD*EE+255)/256, 256, 0, stream>>>(fc1_w, fc1F, EE, DD, EE);
        convT<<<(DD*3728+255)/256, 256, 0, stream>>>(mlp_w0, mlp0F, HDIM, DD, 3728);
        convT<<<(DD*KP300+255)/256, 256, 0, stream>>>(mlp_w1, mlp1F, DD, DD, KP300);
    }
    // 2. H0 = relu(features @ fc1_w + fc1_b) -> Hbuf col 0
    gemm_mfma<<<dim3(5,36),256,0,stream>>>(features, EE, fc1F, EE, fc1_b,
                                           Hbuf, HDIM, DD, EE, 1);
    // 3. features -> Hbuf cols [2700,3724)
    featcopy<<<ROWS,256,0,stream>>>(features, Hbuf);

    for (int l=0;l<LL;l++){
        int ccol  = (l==0)? 0 : 300 + (l-1)*600;
        int hcol  = l*300;
        int pcol  = 600 + l*600;
        int clcol = 300 + l*600;
        const float* pwhT = wT + (size_t)l*DD*G3;
        const half2_t* pwiHl = pwiH + (size_t)l*PP*G3;
        const _Float16* pwhF = gruF + (size_t)(l*3+0)*G3*KP300;
        const _Float16* cwiF = gruF + (size_t)(l*3+1)*G3*KP300;
        const _Float16* cwhF = gruF + (size_t)(l*3+2)*G3*KP300;

        // GHp = Hin @ pwh^T + pbh
        gemm_mfma<<<dim3(15,36),256,0,stream>>>(Hbuf+hcol, HDIM, pwhF, KP300,
                                                gp_bhh + l*G3, bufA, G3, G3, DD, 0);
        // qdot = Cin·wq + gb
        qdot_kernel<<<1152,256,0,stream>>>(Hbuf, ccol, gat_wq + l*DD, gat_b, l, qd);
        // sequential p-scan
        scan_kernel<<<BB,1024,0,stream>>>(Hbuf, bufA, pwiHl, pwhT,
                                          gp_bih + l*G3, gp_bhh + l*G3,
                                          gat_wk + l*DD, qd, adj, Mbuf,
                                          ccol, hcol, pcol);
        // GIc = Cin @ cwi^T + cbi
        gemm_mfma<<<dim3(15,36),256,0,stream>>>(Hbuf+ccol, HDIM, cwiF, KP300,
                                                gc_bih + l*G3, bufB, G3, G3, DD, 0);
        // GHc = M @ cwh^T + cbh
        gemm_mfma<<<dim3(15,36),256,0,stream>>>(Mbuf, DD, cwhF, KP300,
                                                gc_bhh + l*G3, bufC, G3, G3, DD, 0);
        // CL = GRU-combine
        combine_c<<<ROWS,320,0,stream>>>(bufB, bufC, Mbuf, Hbuf, clcol);
    }

    // MLP
    gemm_mfma<<<dim3(5,36),256,0,stream>>>(Hbuf, HDIM, mlp0F, 3728, mlp_b0,
                                           bufB, DD, DD, HDIM, 1);
    gemm_mfma<<<dim3(5,36),256,0,stream>>>(bufB, DD, mlp1F, KP300, mlp_b1,
                                           bufC, DD, DD, DD, 1);
    logits_kernel<<<ROWS,64,0,stream>>>(bufC, mlp_w2, mlp_b2, out);
}

// Round 8
// 3496.930 us; speedup vs baseline: 1.6546x; 1.1085x over previous
//
#include <hip/hip_runtime.h>
#include <math.h>

#define BB 48
#define NN 96
#define EE 1024
#define DD 300
#define LL 4
#define G3 900          // 3*D
#define PP 150          // DD/2 f16 pairs
#define PP2 152         // padded pairs (38 chunks of 4)
#define NC4 38          // weight chunks of 4 pairs
#define HDIM 3724       // D*(2L+1)+E
#define ROWS (BB*NN)    // 4608
#define NEGI -1.0e30f
#define KP300 304       // 300 padded to mult-of-8

typedef _Float16 half2_t __attribute__((ext_vector_type(2)));
typedef _Float16 h8 __attribute__((ext_vector_type(8)));
typedef float f4 __attribute__((ext_vector_type(4)));

__device__ __forceinline__ float sigm(float x){ return 1.0f/(1.0f+expf(-x)); }

// ---------------- transpose pwh (900,300) -> pwhT (300,900), fp32, scan-init only ----------------
__global__ void transpose_w(const float* __restrict__ gp_whh, float* __restrict__ wT)
{
    __shared__ float tile[32][33];
    int l = blockIdx.z;
    const float* src = gp_whh + (size_t)l*G3*DD;
    float* dst = wT + (size_t)l*DD*G3;
    int g0 = blockIdx.x*32;        // along 900
    int d0 = blockIdx.y*32;        // along 300
    int tx = threadIdx.x, ty = threadIdx.y;   // (32,8)
    #pragma unroll
    for (int r=0;r<32;r+=8){
        int g = g0+ty+r, d = d0+tx;
        tile[ty+r][tx] = (g<G3 && d<DD) ? src[(size_t)g*DD+d] : 0.f;
    }
    __syncthreads();
    #pragma unroll
    for (int r=0;r<32;r+=8){
        int d = d0+ty+r, g = g0+tx;
        if (d<DD && g<G3) dst[(size_t)d*G3+g] = tile[tx][ty+r];
    }
}

// ---------------- pack pwi (L,900,300) -> coalesced h8 chunks (L,38,900) ----------------
// pwiQ[l][c][gate] = f16 of dims 8c..8c+7 of W[gate][:], zero-padded past 300.
__global__ __launch_bounds__(256) void pack_pwi_q(const float* __restrict__ gp_wih,
                                                  h8* __restrict__ pwiQ)
{
    int l = blockIdx.y;
    int idx = blockIdx.x*256 + threadIdx.x;
    if (idx >= NC4*G3) return;
    int c = idx / G3, gate = idx % G3;
    const float* src = gp_wih + (size_t)l*G3*DD + (size_t)gate*DD;
    h8 v;
    #pragma unroll
    for (int j=0;j<8;j++){
        int d = 8*c + j;
        v[j] = (d<DD) ? (_Float16)src[d] : (_Float16)0.f;
    }
    pwiQ[(size_t)l*NC4*G3 + idx] = v;
}

// ---------------- GRU weights [900][300] fp32 -> [900][304] f16 (zero-padded) ----------------
// z = l*3 + {0:pwh, 1:cwi, 2:cwh}
__global__ __launch_bounds__(256) void conv_gru_w(const float* __restrict__ gp_whh,
                                                  const float* __restrict__ gc_wih,
                                                  const float* __restrict__ gc_whh,
                                                  _Float16* __restrict__ outp)
{
    int z = blockIdx.y; int l = z/3, wsel = z%3;
    const float* src = (wsel==0?gp_whh:wsel==1?gc_wih:gc_whh) + (size_t)l*G3*DD;
    _Float16* dst = outp + (size_t)z*G3*KP300;
    int idx = blockIdx.x*256 + threadIdx.x;
    if (idx >= G3*KP300) return;
    int n = idx/KP300, k = idx%KP300;
    dst[idx] = (k<DD) ? (_Float16)src[(size_t)n*DD+k] : (_Float16)0.f;
}

// ---------------- transpose-convert [K][N] fp32 -> [N][Kpad] f16 ----------------
__global__ __launch_bounds__(256) void convT(const float* __restrict__ src,
                                             _Float16* __restrict__ dst,
                                             int K, int N, int Kpad)
{
    int idx = blockIdx.x*256 + threadIdx.x;
    if (idx >= N*Kpad) return;
    int n = idx/Kpad, k = idx%Kpad;
    dst[idx] = (k<K) ? (_Float16)src[(size_t)k*N + n] : (_Float16)0.f;
}

// ---------------- MFMA f16 GEMM: C(M x N) = act(A_f32 * B^T + bias) ----------------
__global__ __launch_bounds__(256) void gemm_mfma(
    const float* __restrict__ A, int lda,
    const _Float16* __restrict__ B, int Kpad,
    const float* __restrict__ bias,
    float* __restrict__ C, int ldc,
    int N, int K, int relu)
{
    constexpr int BM=128, BN=64, BK=32, KPS=40;
    __shared__ _Float16 As[BM][KPS];
    __shared__ _Float16 Bs[BN][KPS];
    int tid = threadIdx.x;
    int m0 = blockIdx.y*BM, n0 = blockIdx.x*BN;
    int w = tid>>6, lane = tid&63;
    int wy = w>>1, wx = w&1;
    int lm = lane&15, q = lane>>4;

    f4 acc[4][2];
    #pragma unroll
    for (int a=0;a<4;a++)
        #pragma unroll
        for (int b=0;b<2;b++)
            #pragma unroll
            for (int r=0;r<4;r++) acc[a][b][r]=0.f;

    int am = tid>>1, akg = (tid&1)*16;
    int bn = tid>>2, bkg = (tid&3)*8;
    const float* arow = A + (size_t)(m0+am)*lda;

    for (int k0=0; k0<K; k0+=BK){
        {
            __align__(16) _Float16 av[16];
            #pragma unroll
            for (int u=0;u<16;u+=4){
                int k = k0 + akg + u;
                float x0,x1,x2,x3;
                if (k+4 <= K){
                    float4 v = *(const float4*)(arow + k);
                    x0=v.x;x1=v.y;x2=v.z;x3=v.w;
                } else {
                    x0 = (k  <K)? arow[k  ]:0.f;
                    x1 = (k+1<K)? arow[k+1]:0.f;
                    x2 = (k+2<K)? arow[k+2]:0.f;
                    x3 = (k+3<K)? arow[k+3]:0.f;
                }
                av[u]=(_Float16)x0; av[u+1]=(_Float16)x1;
                av[u+2]=(_Float16)x2; av[u+3]=(_Float16)x3;
            }
            *(h8*)&As[am][akg]   = *(h8*)&av[0];
            *(h8*)&As[am][akg+8] = *(h8*)&av[8];
        }
        {
            int gk = k0 + bkg;
            h8 bv;
            #pragma unroll
            for (int j=0;j<8;j++) bv[j]=(_Float16)0.f;
            if (n0+bn < N && gk < Kpad)
                bv = *(const h8*)(B + (size_t)(n0+bn)*Kpad + gk);
            *(h8*)&Bs[bn][bkg] = bv;
        }
        __syncthreads();
        h8 af[4], bf[2];
        #pragma unroll
        for (int mb=0; mb<4; mb++) af[mb] = *(h8*)&As[wy*64+mb*16+lm][q*8];
        #pragma unroll
        for (int nb=0; nb<2; nb++) bf[nb] = *(h8*)&Bs[wx*32+nb*16+lm][q*8];
        #pragma unroll
        for (int mb=0; mb<4; mb++)
            #pragma unroll
            for (int nb=0; nb<2; nb++)
                acc[mb][nb] = __builtin_amdgcn_mfma_f32_16x16x32_f16(af[mb], bf[nb], acc[mb][nb], 0,0,0);
        __syncthreads();
    }
    #pragma unroll
    for (int mb=0; mb<4; mb++){
        int r0 = m0 + wy*64 + mb*16 + q*4;
        #pragma unroll
        for (int nb=0; nb<2; nb++){
            int c = n0 + wx*32 + nb*16 + lm;
            if (c < N){
                float bb = bias[c];
                #pragma unroll
                for (int reg=0; reg<4; reg++){
                    float v = acc[mb][nb][reg] + bb;
                    if (relu) v = fmaxf(v, 0.f);
                    C[(size_t)(r0+reg)*ldc + c] = v;
                }
            }
        }
    }
}

// ---------------- copy features into last 1024 cols of Hbuf ----------------
__global__ void featcopy(const float* __restrict__ f, float* __restrict__ H)
{
    size_t row = blockIdx.x;
    int t = threadIdx.x;
    float4 v = *(const float4*)(f + row*EE + t*4);
    *(float4*)(H + row*HDIM + 2700 + t*4) = v;
}

// ---------------- qdot[r] = Cin[r,:]·wq + gb ----------------
__global__ __launch_bounds__(256) void qdot_kernel(
    const float* __restrict__ Hbuf, int ccol,
    const float* __restrict__ wq, const float* __restrict__ gat_b, int l,
    float* __restrict__ qd)
{
    int row = blockIdx.x*4 + (threadIdx.x>>6);
    int lane = threadIdx.x & 63;
    const float* x = Hbuf + (size_t)row*HDIM + ccol;
    float s = 0.f;
    for (int d=lane; d<DD; d+=64) s += x[d]*wq[d];
    #pragma unroll
    for (int o=32;o>0;o>>=1) s += __shfl_down(s,o);
    if (lane==0) qd[row] = s + gat_b[l];
}

// ---------------- the sequential p-scan: one block per batch element ----------------
// Phase D: coalesced h8 weight chunks (16 B/lane, global_load_dwordx4),
// M via same-address ds_read_b128 broadcasts. No register-resident weights (spills).
__global__ __launch_bounds__(1024) void scan_kernel(
    float* __restrict__ Hbuf,
    const float* __restrict__ GHp,        // (4608,900) = Hin@pwh^T + pbh
    const h8* __restrict__ pwiQ,          // (38,900) h8 chunks
    const float* __restrict__ pwhT,       // (300,900) fp32 (init only)
    const float* __restrict__ pbi,        // (900)
    const float* __restrict__ pbh,        // (900)
    const float* __restrict__ wk,         // (300)
    const float* __restrict__ qd,         // (4608), includes +gb
    const float* __restrict__ adj,        // (48,96,96)
    float* __restrict__ Mbuf,             // (4608,300)
    int ccol, int hcol, int pcol)
{
    int b = blockIdx.x;
    int t = threadIdx.x;

    __shared__ __align__(16) half2_t P_h2[NN][PP];   // 57600 B
    __shared__ __align__(16) float g_s[G3];
    __shared__ __align__(16) float Mpart[3][DD];
    __shared__ __align__(16) half2_t M_h2[PP2];      // padded to 152 pairs
    __shared__ __align__(16) float e_s[NN];
    __shared__ __align__(16) float pk_s[NN];
    __shared__ __align__(16) float pw_s[DD];
    __shared__ __align__(16) float adj_s[NN*NN];
    __shared__ __align__(16) float qd_s[NN];
    __shared__ __align__(16) float ghp_s[G3];
    __shared__ __align__(16) float hv_s[DD];

    size_t rowbase = (size_t)b*NN;

    for (int k=t; k<NN*NN; k+=1024) adj_s[k] = adj[rowbase*NN + k];
    if (t < NN) qd_s[t] = qd[rowbase + t];
    if (t >= PP && t < PP2){                 // zero the pad pairs once
        half2_t z; z.x=(_Float16)0.f; z.y=(_Float16)0.f;
        M_h2[t] = z;
    }

    if (t < DD) Mpart[0][t] = Hbuf[rowbase*HDIM + ccol + t];   // Cin0
    __syncthreads();
    if (t < G3){
        float acc = pbh[t];
        #pragma unroll 4
        for (int d=0; d<DD; d++) acc += Mpart[0][d]*pwhT[(size_t)d*G3+t];
        g_s[t] = acc;
    }
    __syncthreads();
    if (t < PP){
        int d0 = 2*t, d1 = 2*t+1;
        float r0  = sigm(pbi[d0]      + g_s[d0]);
        float z0  = sigm(pbi[DD+d0]   + g_s[DD+d0]);
        float n0  = tanhf(pbi[2*DD+d0] + r0*g_s[2*DD+d0]);
        float p0  = (1.f-z0)*n0 + z0*Mpart[0][d0];
        float r1  = sigm(pbi[d1]      + g_s[d1]);
        float z1  = sigm(pbi[DD+d1]   + g_s[DD+d1]);
        float n1  = tanhf(pbi[2*DD+d1] + r1*g_s[2*DD+d1]);
        float p1  = (1.f-z1)*n1 + z1*Mpart[0][d1];
        *(float2*)&Hbuf[rowbase*HDIM + pcol + d0] = make_float2(p0,p1);
        half2_t ph; ph.x = (_Float16)p0; ph.y = (_Float16)p1;
        P_h2[0][t] = ph;
        pw_s[d0] = p0*wk[d0];
        pw_s[d1] = p1*wk[d1];
        *(float2*)&Mbuf[rowbase*DD + d0] = make_float2(0.f,0.f);
    }
    __syncthreads();

    for (int i=1;i<NN;i++){
        size_t row = rowbase + i;
        // ---- AB (wave 0): pk reduce + logits + softmax
        if (t < 64){
            float s = 0.f;
            for (int c=t;c<DD;c+=64) s += pw_s[c];
            #pragma unroll
            for (int o=32;o>0;o>>=1) s += __shfl_xor(s,o);
            if (t==0) pk_s[i-1] = s;
            float q = qd_s[i];
            float a0 = NEGI, a1 = NEGI;
            if (t < i){
                if (adj_s[i*NN+t] != 0.f) a0 = q + ((t==i-1)? s : pk_s[t]);
            }
            int j1 = 64+t;
            if (t < 32 && j1 < i){
                if (adj_s[i*NN+j1] != 0.f) a1 = q + ((j1==i-1)? s : pk_s[j1]);
            }
            float m = fmaxf(a0,a1);
            #pragma unroll
            for (int o=32;o>0;o>>=1) m = fmaxf(m, __shfl_xor(m,o));
            float e0 = expf(a0-m);
            float e1 = (t<32)? expf(a1-m) : 0.f;
            float ss = e0+e1;
            #pragma unroll
            for (int o=32;o>0;o>>=1) ss += __shfl_xor(ss,o);
            float inv = 1.f/ss;
            e_s[t] = e0*inv;
            if (t<32) e_s[64+t] = e1*inv;
        }
        __syncthreads();
        // ---- C (t<450): 3-way j-split weighted sum of LDS P rows; prefetchers (t>=512)
        if (t < 450){
            int g = t/150, dp = t%150;
            int cnt = (i+2)/3;
            int j0 = g*cnt; int j1 = j0+cnt; if (j1 > i) j1 = i;
            float m0=0.f, m1=0.f;
            for (int j=j0;j<j1;j++){
                float w = e_s[j];
                half2_t pv = P_h2[j][dp];
                m0 += w*(float)pv.x;
                m1 += w*(float)pv.y;
            }
            *(float2*)&Mpart[g][2*dp] = make_float2(m0,m1);
        } else if (t >= 512){
            int k = t-512;
            #pragma unroll
            for (int it=0; it<2; it++){
                int idx = k + it*512;
                if (idx < 450){
                    *(float2*)&ghp_s[2*idx] = *(const float2*)&GHp[row*G3 + 2*idx];
                } else if (idx < 600){
                    int h = idx-450;
                    *(float2*)&hv_s[2*h] = *(const float2*)&Hbuf[row*HDIM + hcol + 2*h];
                }
            }
        }
        __syncthreads();
        // ---- Csum (t<150): combine partials, write Mbuf + f16 M
        if (t < PP){
            float m0 = Mpart[0][2*t] + Mpart[1][2*t] + Mpart[2][2*t];
            float m1 = Mpart[0][2*t+1] + Mpart[1][2*t+1] + Mpart[2][2*t+1];
            half2_t mh; mh.x = (_Float16)m0; mh.y = (_Float16)m1;
            M_h2[t] = mh;
            *(float2*)&Mbuf[row*DD + 2*t] = make_float2(m0,m1);
        }
        __syncthreads();
        // ---- D (t<900): g = M @ pwi^T + pbi; 38 coalesced h8 chunks
        if (t < G3){
            const h8* W = pwiQ + t;           // chunk stride G3
            float a0=0.f, a1=0.f, a2=0.f, a3=0.f;
            #pragma unroll 4
            for (int c=0;c<NC4;c++){
                h8 wv = W[(size_t)c*G3];      // global_load_dwordx4, 16 B/lane coalesced
                h8 mc = *(h8*)&M_h2[4*c];     // same-address ds_read_b128 broadcast
                half2_t w0,w1,w2,w3,m0,m1,m2,m3;
                w0.x=wv[0]; w0.y=wv[1]; m0.x=mc[0]; m0.y=mc[1];
                w1.x=wv[2]; w1.y=wv[3]; m1.x=mc[2]; m1.y=mc[3];
                w2.x=wv[4]; w2.y=wv[5]; m2.x=mc[4]; m2.y=mc[5];
                w3.x=wv[6]; w3.y=wv[7]; m3.x=mc[6]; m3.y=mc[7];
                a0 = __builtin_amdgcn_fdot2(w0, m0, a0, false);
                a1 = __builtin_amdgcn_fdot2(w1, m1, a1, false);
                a2 = __builtin_amdgcn_fdot2(w2, m2, a2, false);
                a3 = __builtin_amdgcn_fdot2(w3, m3, a3, false);
            }
            g_s[t] = pbi[t] + (a0+a2) + (a1+a3);
        }
        __syncthreads();
        // ---- E (t<150): GRU combine (pure LDS), write P row + pw
        if (t < PP){
            int d0 = 2*t, d1 = 2*t+1;
            float2 hv = *(const float2*)&hv_s[d0];
            float2 wk2 = *(const float2*)&wk[d0];
            float r0  = sigm(g_s[d0]      + ghp_s[d0]);
            float z0  = sigm(g_s[DD+d0]   + ghp_s[DD+d0]);
            float n0  = tanhf(g_s[2*DD+d0] + r0*ghp_s[2*DD+d0]);
            float p0  = (1.f-z0)*n0 + z0*hv.x;
            float r1  = sigm(g_s[d1]      + ghp_s[d1]);
            float z1  = sigm(g_s[DD+d1]   + ghp_s[DD+d1]);
            float n1  = tanhf(g_s[2*DD+d1] + r1*ghp_s[2*DD+d1]);
            float p1  = (1.f-z1)*n1 + z1*hv.y;
            *(float2*)&Hbuf[row*HDIM + pcol + d0] = make_float2(p0,p1);
            half2_t ph; ph.x = (_Float16)p0; ph.y = (_Float16)p1;
            P_h2[i][t] = ph;
            pw_s[d0] = p0*wk2.x;
            pw_s[d1] = p1*wk2.y;
        }
        __syncthreads();
    }
}

// ---------------- c-side elementwise combine ----------------
__global__ __launch_bounds__(320) void combine_c(
    const float* __restrict__ GIc, const float* __restrict__ GHc,
    const float* __restrict__ Mbuf, float* __restrict__ Hbuf, int clcol)
{
    size_t row = blockIdx.x;
    int d = threadIdx.x;
    if (d < DD){
        float ir = GIc[row*G3+d], iz = GIc[row*G3+DD+d], inn = GIc[row*G3+2*DD+d];
        float hr = GHc[row*G3+d], hz = GHc[row*G3+DD+d], hn  = GHc[row*G3+2*DD+d];
        float r  = sigm(ir+hr);
        float z  = sigm(iz+hz);
        float nn = tanhf(inn + r*hn);
        float h  = Mbuf[row*DD+d];
        Hbuf[row*HDIM + clcol + d] = (1.f-z)*nn + z*h;
    }
}

// ---------------- logits: out = x2 @ w2 + b2 (N=7) ----------------
__global__ __launch_bounds__(64) void logits_kernel(
    const float* __restrict__ x2, const float* __restrict__ w2,
    const float* __restrict__ b2, float* __restrict__ out)
{
    size_t row = blockIdx.x;
    int lane = threadIdx.x;
    float acc[7]={0,0,0,0,0,0,0};
    for (int d=lane; d<DD; d+=64){
        float x = x2[row*DD+d];
        #pragma unroll
        for (int c=0;c<7;c++) acc[c] += x*w2[d*7+c];
    }
    #pragma unroll
    for (int c=0;c<7;c++){
        float s = acc[c];
        #pragma unroll
        for (int o=32;o>0;o>>=1) s += __shfl_down(s,o);
        if (lane==0) out[row*7+c] = s + b2[c];
    }
}

extern "C" void kernel_launch(void* const* d_in, const int* in_sizes, int n_in,
                              void* d_out, int out_size, void* d_ws, size_t ws_size,
                              hipStream_t stream)
{
    const float* features = (const float*)d_in[0];
    const float* adj      = (const float*)d_in[1];
    const float* fc1_w    = (const float*)d_in[3];
    const float* fc1_b    = (const float*)d_in[4];
    const float* gc_wih   = (const float*)d_in[5];
    const float* gc_whh   = (const float*)d_in[6];
    const float* gc_bih   = (const float*)d_in[7];
    const float* gc_bhh   = (const float*)d_in[8];
    const float* gp_wih   = (const float*)d_in[9];
    const float* gp_whh   = (const float*)d_in[10];
    const float* gp_bih   = (const float*)d_in[11];
    const float* gp_bhh   = (const float*)d_in[12];
    const float* gat_wq   = (const float*)d_in[13];
    const float* gat_wk   = (const float*)d_in[14];
    const float* gat_b    = (const float*)d_in[15];
    const float* mlp_w0   = (const float*)d_in[16];
    const float* mlp_b0   = (const float*)d_in[17];
    const float* mlp_w1   = (const float*)d_in[18];
    const float* mlp_b1   = (const float*)d_in[19];
    const float* mlp_w2   = (const float*)d_in[20];
    const float* mlp_b2   = (const float*)d_in[21];
    float* out = (float*)d_out;

    float* ws = (float*)d_ws;
    size_t off = 0;
    float* Hbuf = ws + off; off += (size_t)ROWS*HDIM;
    float* bufA = ws + off; off += (size_t)ROWS*G3;    // GHp
    float* bufB = ws + off; off += (size_t)ROWS*G3;    // GIc / x1
    float* bufC = ws + off; off += (size_t)ROWS*G3;    // GHc / x2
    float* Mbuf = ws + off; off += (size_t)ROWS*DD;
    float* qd   = ws + off; off += ROWS;
    float* wT   = ws + off; off += (size_t)LL*DD*G3;               // pwhT fp32 (scan init)
    h8* pwiQ = (h8*)(ws + off); off += (size_t)LL*NC4*G3*4;        // h8 = 4 floats
    _Float16* gruF = (_Float16*)(ws + off); off += (size_t)12*G3*KP300/2;  // 12x [900][304] f16
    _Float16* fc1F = (_Float16*)(ws + off); off += (size_t)DD*EE/2;        // [300][1024]
    _Float16* mlp0F= (_Float16*)(ws + off); off += (size_t)DD*3728/2;      // [300][3728]
    _Float16* mlp1F= (_Float16*)(ws + off); off += (size_t)DD*KP300/2;     // [300][304]
    (void)ws_size; (void)in_sizes; (void)n_in; (void)out_size;

    // 1. weight prep
    {
        dim3 g((G3+31)/32, (DD+31)/32, LL);
        dim3 bl(32,8);
        transpose_w<<<g, bl, 0, stream>>>(gp_whh, wT);
        pack_pwi_q<<<dim3((NC4*G3+255)/256, LL), 256, 0, stream>>>(gp_wih, pwiQ);
        conv_gru_w<<<dim3((G3*KP300+255)/256, 12), 256, 0, stream>>>(gp_whh, gc_wih, gc_whh, gruF);
        convT<<<(DD*EE+255)/256, 256, 0, stream>>>(fc1_w, fc1F, EE, DD, EE);
        convT<<<(DD*3728+255)/256, 256, 0, stream>>>(mlp_w0, mlp0F, HDIM, DD, 3728);
        convT<<<(DD*KP300+255)/256, 256, 0, stream>>>(mlp_w1, mlp1F, DD, DD, KP300);
    }
    // 2. H0 = relu(features @ fc1_w + fc1_b) -> Hbuf col 0
    gemm_mfma<<<dim3(5,36),256,0,stream>>>(features, EE, fc1F, EE, fc1_b,
                                           Hbuf, HDIM, DD, EE, 1);
    // 3. features -> Hbuf cols [2700,3724)
    featcopy<<<ROWS,256,0,stream>>>(features, Hbuf);

    for (int l=0;l<LL;l++){
        int ccol  = (l==0)? 0 : 300 + (l-1)*600;
        int hcol  = l*300;
        int pcol  = 600 + l*600;
        int clcol = 300 + l*600;
        const float* pwhT = wT + (size_t)l*DD*G3;
        const h8* pwiQl = pwiQ + (size_t)l*NC4*G3;
        const _Float16* pwhF = gruF + (size_t)(l*3+0)*G3*KP300;
        const _Float16* cwiF = gruF + (size_t)(l*3+1)*G3*KP300;
        const _Float16* cwhF = gruF + (size_t)(l*3+2)*G3*KP300;

        // GHp = Hin @ pwh^T + pbh
        gemm_mfma<<<dim3(15,36),256,0,stream>>>(Hbuf+hcol, HDIM, pwhF, KP300,
                                                gp_bhh + l*G3, bufA, G3, G3, DD, 0);
        // qdot = Cin·wq + gb
        qdot_kernel<<<1152,256,0,stream>>>(Hbuf, ccol, gat_wq + l*DD, gat_b, l, qd);
        // sequential p-scan
        scan_kernel<<<BB,1024,0,stream>>>(Hbuf, bufA, pwiQl, pwhT,
                                          gp_bih + l*G3, gp_bhh + l*G3,
                                          gat_wk + l*DD, qd, adj, Mbuf,
                                          ccol, hcol, pcol);
        // GIc = Cin @ cwi^T + cbi
        gemm_mfma<<<dim3(15,36),256,0,stream>>>(Hbuf+ccol, HDIM, cwiF, KP300,
                                                gc_bih + l*G3, bufB, G3, G3, DD, 0);
        // GHc = M @ cwh^T + cbh
        gemm_mfma<<<dim3(15,36),256,0,stream>>>(Mbuf, DD, cwhF, KP300,
                                                gc_bhh + l*G3, bufC, G3, G3, DD, 0);
        // CL = GRU-combine
        combine_c<<<ROWS,320,0,stream>>>(bufB, bufC, Mbuf, Hbuf, clcol);
    }

    // MLP
    gemm_mfma<<<dim3(5,36),256,0,stream>>>(Hbuf, HDIM, mlp0F, 3728, mlp_b0,
                                           bufB, DD, DD, HDIM, 1);
    gemm_mfma<<<dim3(5,36),256,0,stream>>>(bufB, DD, mlp1F, KP300, mlp_b1,
                                           bufC, DD, DD, DD, 1);
    logits_kernel<<<ROWS,64,0,stream>>>(bufC, mlp_w2, mlp_b2, out);
}

// Round 9
// 3314.230 us; speedup vs baseline: 1.7458x; 1.0551x over previous
//
#include <hip/hip_runtime.h>
#include <math.h>

#define BB 48
#define NN 96
#define EE 1024
#define DD 300
#define LL 4
#define G3 900          // 3*D
#define PP 150          // DD/2 f16 pairs
#define PP2 152         // padded pairs (38 chunks of 4)
#define NC4 38          // weight chunks of 4 pairs
#define HDIM 3724       // D*(2L+1)+E
#define ROWS (BB*NN)    // 4608
#define NEGI -1.0e30f
#define KP300 304       // 300 padded to mult-of-8
#define GIC_TILES 540   // 15 x 36 tiles for fused GIc GEMM

typedef _Float16 half2_t __attribute__((ext_vector_type(2)));
typedef _Float16 h8 __attribute__((ext_vector_type(8)));
typedef float f4 __attribute__((ext_vector_type(4)));

__device__ __forceinline__ float sigm(float x){ return 1.0f/(1.0f+expf(-x)); }

// ---------------- pack W (L,900,300) -> coalesced h8 chunks (L,38,900) ----------------
// dst[l][c][gate] = f16 of dims 8c..8c+7 of W[gate][:], zero-padded past 300.
__global__ __launch_bounds__(256) void pack_w_q(const float* __restrict__ src_all,
                                                h8* __restrict__ dst)
{
    int l = blockIdx.y;
    int idx = blockIdx.x*256 + threadIdx.x;
    if (idx >= NC4*G3) return;
    int c = idx / G3, gate = idx % G3;
    const float* src = src_all + (size_t)l*G3*DD + (size_t)gate*DD;
    h8 v;
    #pragma unroll
    for (int j=0;j<8;j++){
        int d = 8*c + j;
        v[j] = (d<DD) ? (_Float16)src[d] : (_Float16)0.f;
    }
    dst[(size_t)l*NC4*G3 + idx] = v;
}

// ---------------- GRU weights [900][300] fp32 -> [900][304] f16 (zero-padded) ----------------
// z = l*3 + {0:pwh, 1:cwi, 2:cwh}
__global__ __launch_bounds__(256) void conv_gru_w(const float* __restrict__ gp_whh,
                                                  const float* __restrict__ gc_wih,
                                                  const float* __restrict__ gc_whh,
                                                  _Float16* __restrict__ outp)
{
    int z = blockIdx.y; int l = z/3, wsel = z%3;
    const float* src = (wsel==0?gp_whh:wsel==1?gc_wih:gc_whh) + (size_t)l*G3*DD;
    _Float16* dst = outp + (size_t)z*G3*KP300;
    int idx = blockIdx.x*256 + threadIdx.x;
    if (idx >= G3*KP300) return;
    int n = idx/KP300, k = idx%KP300;
    dst[idx] = (k<DD) ? (_Float16)src[(size_t)n*DD+k] : (_Float16)0.f;
}

// ---------------- transpose-convert [K][N] fp32 -> [N][Kpad] f16 ----------------
__global__ __launch_bounds__(256) void convT(const float* __restrict__ src,
                                             _Float16* __restrict__ dst,
                                             int K, int N, int Kpad)
{
    int idx = blockIdx.x*256 + threadIdx.x;
    if (idx >= N*Kpad) return;
    int n = idx/Kpad, k = idx%Kpad;
    dst[idx] = (k<K) ? (_Float16)src[(size_t)k*N + n] : (_Float16)0.f;
}

// ---------------- MFMA f16 GEMM tile body (device fn, 256 active threads) ----------------
__device__ __forceinline__ void gemm_tile(
    int m0, int n0, int tid,
    const float* __restrict__ A, int lda,
    const _Float16* __restrict__ B, int Kpad,
    const float* __restrict__ bias,
    float* __restrict__ C, int ldc,
    int N, int K, int relu)
{
    constexpr int KPS=40;
    __shared__ _Float16 As[128][KPS];
    __shared__ _Float16 Bs[64][KPS];
    int w = tid>>6, lane = tid&63;
    int wy = w>>1, wx = w&1;
    int lm = lane&15, q = lane>>4;

    f4 acc[4][2];
    #pragma unroll
    for (int a=0;a<4;a++)
        #pragma unroll
        for (int b=0;b<2;b++)
            #pragma unroll
            for (int r=0;r<4;r++) acc[a][b][r]=0.f;

    int am = tid>>1, akg = (tid&1)*16;
    int bn = tid>>2, bkg = (tid&3)*8;
    const float* arow = A + (size_t)(m0+am)*lda;

    for (int k0=0; k0<K; k0+=32){
        {
            __align__(16) _Float16 av[16];
            #pragma unroll
            for (int u=0;u<16;u+=4){
                int k = k0 + akg + u;
                float x0,x1,x2,x3;
                if (k+4 <= K){
                    float4 v = *(const float4*)(arow + k);
                    x0=v.x;x1=v.y;x2=v.z;x3=v.w;
                } else {
                    x0 = (k  <K)? arow[k  ]:0.f;
                    x1 = (k+1<K)? arow[k+1]:0.f;
                    x2 = (k+2<K)? arow[k+2]:0.f;
                    x3 = (k+3<K)? arow[k+3]:0.f;
                }
                av[u]=(_Float16)x0; av[u+1]=(_Float16)x1;
                av[u+2]=(_Float16)x2; av[u+3]=(_Float16)x3;
            }
            *(h8*)&As[am][akg]   = *(h8*)&av[0];
            *(h8*)&As[am][akg+8] = *(h8*)&av[8];
        }
        {
            int gk = k0 + bkg;
            h8 bv;
            #pragma unroll
            for (int j=0;j<8;j++) bv[j]=(_Float16)0.f;
            if (n0+bn < N && gk < Kpad)
                bv = *(const h8*)(B + (size_t)(n0+bn)*Kpad + gk);
            *(h8*)&Bs[bn][bkg] = bv;
        }
        __syncthreads();
        h8 af[4], bf[2];
        #pragma unroll
        for (int mb=0; mb<4; mb++) af[mb] = *(h8*)&As[wy*64+mb*16+lm][q*8];
        #pragma unroll
        for (int nb=0; nb<2; nb++) bf[nb] = *(h8*)&Bs[wx*32+nb*16+lm][q*8];
        #pragma unroll
        for (int mb=0; mb<4; mb++)
            #pragma unroll
            for (int nb=0; nb<2; nb++)
                acc[mb][nb] = __builtin_amdgcn_mfma_f32_16x16x32_f16(af[mb], bf[nb], acc[mb][nb], 0,0,0);
        __syncthreads();
    }
    #pragma unroll
    for (int mb=0; mb<4; mb++){
        int r0 = m0 + wy*64 + mb*16 + q*4;
        #pragma unroll
        for (int nb=0; nb<2; nb++){
            int c = n0 + wx*32 + nb*16 + lm;
            if (c < N){
                float bb = bias[c];
                #pragma unroll
                for (int reg=0; reg<4; reg++){
                    float v = acc[mb][nb][reg] + bb;
                    if (relu) v = fmaxf(v, 0.f);
                    C[(size_t)(r0+reg)*ldc + c] = v;
                }
            }
        }
    }
}

// ---------------- standalone MFMA GEMM kernel (GHp, GHc, MLP, H0) ----------------
__global__ __launch_bounds__(256) void gemm_mfma(
    const float* __restrict__ A, int lda,
    const _Float16* __restrict__ B, int Kpad,
    const float* __restrict__ bias,
    float* __restrict__ C, int ldc,
    int N, int K, int relu)
{
    gemm_tile(blockIdx.y*128, blockIdx.x*64, threadIdx.x,
              A, lda, B, Kpad, bias, C, ldc, N, K, relu);
}

// ---------------- copy features into last 1024 cols of Hbuf ----------------
__global__ void featcopy(const float* __restrict__ f, float* __restrict__ H)
{
    size_t row = blockIdx.x;
    int t = threadIdx.x;
    float4 v = *(const float4*)(f + row*EE + t*4);
    *(float4*)(H + row*HDIM + 2700 + t*4) = v;
}

// ---------------- fused scan + GIc GEMM ----------------
// blocks 0..47: sequential p-scan (one per batch). blocks 48..587: GIc GEMM tiles
// (GIc = Cin @ cwi^T + cbi — depends only on Cin, ready at launch; runs on idle CUs).
__global__ __launch_bounds__(1024) void scan_kernel(
    float* __restrict__ Hbuf,
    const float* __restrict__ GHp,        // (4608,900) = Hin@pwh^T + pbh
    const h8* __restrict__ pwiQ,          // (38,900) h8 chunks of pwi
    const h8* __restrict__ pwhQ,          // (38,900) h8 chunks of pwh (init)
    const float* __restrict__ pbi,        // (900)
    const float* __restrict__ pbh,        // (900)
    const float* __restrict__ wk,         // (300) gat_wk row
    const float* __restrict__ wq,         // (300) gat_wq row
    const float* __restrict__ gat_b, int lidx,
    const float* __restrict__ adj,        // (48,96,96)
    float* __restrict__ Mbuf,             // (4608,300)
    int ccol, int hcol, int pcol,
    const _Float16* __restrict__ cwiF,    // [900][304] f16 (GIc weights)
    const float* __restrict__ cbi,        // (900)
    float* __restrict__ GIc)              // (4608,900) out
{
    // ---- GEMM blocks ----
    if (blockIdx.x >= BB){
        if (threadIdx.x < 256){
            int bid = blockIdx.x - BB;
            int n0 = (bid % 15)*64, m0 = (bid / 15)*128;
            gemm_tile(m0, n0, threadIdx.x, Hbuf + ccol, HDIM, cwiF, KP300,
                      cbi, GIc, G3, G3, DD, 0);
        }
        return;
    }

    int b = blockIdx.x;
    int t = threadIdx.x;

    __shared__ __align__(16) half2_t P_h2[NN][PP];   // 57600 B
    __shared__ __align__(16) float g_s[G3];
    __shared__ __align__(16) float Mpart[3][DD];
    __shared__ __align__(16) half2_t M_h2[PP2];      // padded to 152 pairs
    __shared__ __align__(16) float e_s[NN];
    __shared__ __align__(16) float pk_s[NN];
    __shared__ __align__(16) float pw_s[DD];
    __shared__ __align__(16) float adj_s[NN*NN];
    __shared__ __align__(16) float qd_s[NN];
    __shared__ __align__(16) float ghp_s[G3];
    __shared__ __align__(16) float hv_s[DD];

    size_t rowbase = (size_t)b*NN;

    // ---- init phase 1: adj staging + local qdot + Cin0 -> M
    for (int k=t; k<NN*NN; k+=1024) adj_s[k] = adj[rowbase*NN + k];
    {
        int w = t>>6, lane = t&63;
        float gb = gat_b[lidx];
        for (int r = w; r < NN; r += 16){
            const float* x = Hbuf + (rowbase + r)*HDIM + ccol;
            float s = 0.f;
            for (int d=lane; d<DD; d+=64) s += x[d]*wq[d];
            #pragma unroll
            for (int o=32;o>0;o>>=1) s += __shfl_xor(s,o);
            if (lane==0) qd_s[r] = s + gb;
        }
    }
    if (t < PP){
        float2 c2 = *(const float2*)&Hbuf[rowbase*HDIM + ccol + 2*t];
        Mpart[0][2*t] = c2.x; Mpart[0][2*t+1] = c2.y;
        half2_t mh; mh.x = (_Float16)c2.x; mh.y = (_Float16)c2.y;
        M_h2[t] = mh;
    } else if (t < PP2){
        half2_t z; z.x=(_Float16)0.f; z.y=(_Float16)0.f;
        M_h2[t] = z;
    }
    __syncthreads();
    // ---- init phase 2: gh0 = Cin0 @ pwh^T + pbh (packed h8 chunks)
    if (t < G3){
        const h8* W = pwhQ + t;
        float a0=0.f, a1=0.f, a2=0.f, a3=0.f;
        #pragma unroll 4
        for (int c=0;c<NC4;c++){
            h8 wv = W[(size_t)c*G3];
            h8 mc = *(h8*)&M_h2[4*c];
            half2_t w0,w1,w2,w3,m0,m1,m2,m3;
            w0.x=wv[0]; w0.y=wv[1]; m0.x=mc[0]; m0.y=mc[1];
            w1.x=wv[2]; w1.y=wv[3]; m1.x=mc[2]; m1.y=mc[3];
            w2.x=wv[4]; w2.y=wv[5]; m2.x=mc[4]; m2.y=mc[5];
            w3.x=wv[6]; w3.y=wv[7]; m3.x=mc[6]; m3.y=mc[7];
            a0 = __builtin_amdgcn_fdot2(w0, m0, a0, false);
            a1 = __builtin_amdgcn_fdot2(w1, m1, a1, false);
            a2 = __builtin_amdgcn_fdot2(w2, m2, a2, false);
            a3 = __builtin_amdgcn_fdot2(w3, m3, a3, false);
        }
        g_s[t] = pbh[t] + (a0+a2) + (a1+a3);
    }
    __syncthreads();
    // ---- init phase 3: p0 = GRU(x=0, h=Cin0); M[b,0]=0
    if (t < PP){
        int d0 = 2*t, d1 = 2*t+1;
        float r0  = sigm(pbi[d0]      + g_s[d0]);
        float z0  = sigm(pbi[DD+d0]   + g_s[DD+d0]);
        float n0  = tanhf(pbi[2*DD+d0] + r0*g_s[2*DD+d0]);
        float p0  = (1.f-z0)*n0 + z0*Mpart[0][d0];
        float r1  = sigm(pbi[d1]      + g_s[d1]);
        float z1  = sigm(pbi[DD+d1]   + g_s[DD+d1]);
        float n1  = tanhf(pbi[2*DD+d1] + r1*g_s[2*DD+d1]);
        float p1  = (1.f-z1)*n1 + z1*Mpart[0][d1];
        *(float2*)&Hbuf[rowbase*HDIM + pcol + d0] = make_float2(p0,p1);
        half2_t ph; ph.x = (_Float16)p0; ph.y = (_Float16)p1;
        P_h2[0][t] = ph;
        pw_s[d0] = p0*wk[d0];
        pw_s[d1] = p1*wk[d1];
        *(float2*)&Mbuf[rowbase*DD + d0] = make_float2(0.f,0.f);
    }
    __syncthreads();

    for (int i=1;i<NN;i++){
        size_t row = rowbase + i;
        // ---- AB (wave 0): pk reduce + logits + softmax
        if (t < 64){
            float s = 0.f;
            for (int c=t;c<DD;c+=64) s += pw_s[c];
            #pragma unroll
            for (int o=32;o>0;o>>=1) s += __shfl_xor(s,o);
            if (t==0) pk_s[i-1] = s;
            float q = qd_s[i];
            float a0 = NEGI, a1 = NEGI;
            if (t < i){
                if (adj_s[i*NN+t] != 0.f) a0 = q + ((t==i-1)? s : pk_s[t]);
            }
            int j1 = 64+t;
            if (t < 32 && j1 < i){
                if (adj_s[i*NN+j1] != 0.f) a1 = q + ((j1==i-1)? s : pk_s[j1]);
            }
            float m = fmaxf(a0,a1);
            #pragma unroll
            for (int o=32;o>0;o>>=1) m = fmaxf(m, __shfl_xor(m,o));
            float e0 = expf(a0-m);
            float e1 = (t<32)? expf(a1-m) : 0.f;
            float ss = e0+e1;
            #pragma unroll
            for (int o=32;o>0;o>>=1) ss += __shfl_xor(ss,o);
            float inv = 1.f/ss;
            e_s[t] = e0*inv;
            if (t<32) e_s[64+t] = e1*inv;
        }
        __syncthreads();
        // ---- C (t<450): 3-way j-split weighted sum of LDS P rows; prefetchers (t>=512)
        if (t < 450){
            int g = t/150, dp = t%150;
            int cnt = (i+2)/3;
            int j0 = g*cnt; int j1 = j0+cnt; if (j1 > i) j1 = i;
            float m0=0.f, m1=0.f;
            for (int j=j0;j<j1;j++){
                float w = e_s[j];
                half2_t pv = P_h2[j][dp];
                m0 += w*(float)pv.x;
                m1 += w*(float)pv.y;
            }
            *(float2*)&Mpart[g][2*dp] = make_float2(m0,m1);
        } else if (t >= 512){
            int k = t-512;
            #pragma unroll
            for (int it=0; it<2; it++){
                int idx = k + it*512;
                if (idx < 450){
                    *(float2*)&ghp_s[2*idx] = *(const float2*)&GHp[row*G3 + 2*idx];
                } else if (idx < 600){
                    int h = idx-450;
                    *(float2*)&hv_s[2*h] = *(const float2*)&Hbuf[row*HDIM + hcol + 2*h];
                }
            }
        }
        __syncthreads();
        // ---- Csum (t<150): combine partials, write Mbuf + f16 M
        if (t < PP){
            float m0 = Mpart[0][2*t] + Mpart[1][2*t] + Mpart[2][2*t];
            float m1 = Mpart[0][2*t+1] + Mpart[1][2*t+1] + Mpart[2][2*t+1];
            half2_t mh; mh.x = (_Float16)m0; mh.y = (_Float16)m1;
            M_h2[t] = mh;
            *(float2*)&Mbuf[row*DD + 2*t] = make_float2(m0,m1);
        }
        __syncthreads();
        // ---- D (t<900): g = M @ pwi^T + pbi; 38 coalesced h8 chunks
        if (t < G3){
            const h8* W = pwiQ + t;
            float a0=0.f, a1=0.f, a2=0.f, a3=0.f;
            #pragma unroll 4
            for (int c=0;c<NC4;c++){
                h8 wv = W[(size_t)c*G3];      // global_load_dwordx4, 16 B/lane coalesced
                h8 mc = *(h8*)&M_h2[4*c];     // same-address ds_read_b128 broadcast
                half2_t w0,w1,w2,w3,m0,m1,m2,m3;
                w0.x=wv[0]; w0.y=wv[1]; m0.x=mc[0]; m0.y=mc[1];
                w1.x=wv[2]; w1.y=wv[3]; m1.x=mc[2]; m1.y=mc[3];
                w2.x=wv[4]; w2.y=wv[5]; m2.x=mc[4]; m2.y=mc[5];
                w3.x=wv[6]; w3.y=wv[7]; m3.x=mc[6]; m3.y=mc[7];
                a0 = __builtin_amdgcn_fdot2(w0, m0, a0, false);
                a1 = __builtin_amdgcn_fdot2(w1, m1, a1, false);
                a2 = __builtin_amdgcn_fdot2(w2, m2, a2, false);
                a3 = __builtin_amdgcn_fdot2(w3, m3, a3, false);
            }
            g_s[t] = pbi[t] + (a0+a2) + (a1+a3);
        }
        __syncthreads();
        // ---- E (t<150): GRU combine (pure LDS), write P row + pw
        if (t < PP){
            int d0 = 2*t, d1 = 2*t+1;
            float2 hv = *(const float2*)&hv_s[d0];
            float2 wk2 = *(const float2*)&wk[d0];
            float r0  = sigm(g_s[d0]      + ghp_s[d0]);
            float z0  = sigm(g_s[DD+d0]   + ghp_s[DD+d0]);
            float n0  = tanhf(g_s[2*DD+d0] + r0*ghp_s[2*DD+d0]);
            float p0  = (1.f-z0)*n0 + z0*hv.x;
            float r1  = sigm(g_s[d1]      + ghp_s[d1]);
            float z1  = sigm(g_s[DD+d1]   + ghp_s[DD+d1]);
            float n1  = tanhf(g_s[2*DD+d1] + r1*ghp_s[2*DD+d1]);
            float p1  = (1.f-z1)*n1 + z1*hv.y;
            *(float2*)&Hbuf[row*HDIM + pcol + d0] = make_float2(p0,p1);
            half2_t ph; ph.x = (_Float16)p0; ph.y = (_Float16)p1;
            P_h2[i][t] = ph;
            pw_s[d0] = p0*wk2.x;
            pw_s[d1] = p1*wk2.y;
        }
        __syncthreads();
    }
}

// ---------------- c-side elementwise combine ----------------
__global__ __launch_bounds__(320) void combine_c(
    const float* __restrict__ GIc, const float* __restrict__ GHc,
    const float* __restrict__ Mbuf, float* __restrict__ Hbuf, int clcol)
{
    size_t row = blockIdx.x;
    int d = threadIdx.x;
    if (d < DD){
        float ir = GIc[row*G3+d], iz = GIc[row*G3+DD+d], inn = GIc[row*G3+2*DD+d];
        float hr = GHc[row*G3+d], hz = GHc[row*G3+DD+d], hn  = GHc[row*G3+2*DD+d];
        float r  = sigm(ir+hr);
        float z  = sigm(iz+hz);
        float nn = tanhf(inn + r*hn);
        float h  = Mbuf[row*DD+d];
        Hbuf[row*HDIM + clcol + d] = (1.f-z)*nn + z*h;
    }
}

// ---------------- logits: out = x2 @ w2 + b2 (N=7) ----------------
__global__ __launch_bounds__(64) void logits_kernel(
    const float* __restrict__ x2, const float* __restrict__ w2,
    const float* __restrict__ b2, float* __restrict__ out)
{
    size_t row = blockIdx.x;
    int lane = threadIdx.x;
    float acc[7]={0,0,0,0,0,0,0};
    for (int d=lane; d<DD; d+=64){
        float x = x2[row*DD+d];
        #pragma unroll
        for (int c=0;c<7;c++) acc[c] += x*w2[d*7+c];
    }
    #pragma unroll
    for (int c=0;c<7;c++){
        float s = acc[c];
        #pragma unroll
        for (int o=32;o>0;o>>=1) s += __shfl_down(s,o);
        if (lane==0) out[row*7+c] = s + b2[c];
    }
}

extern "C" void kernel_launch(void* const* d_in, const int* in_sizes, int n_in,
                              void* d_out, int out_size, void* d_ws, size_t ws_size,
                              hipStream_t stream)
{
    const float* features = (const float*)d_in[0];
    const float* adj      = (const float*)d_in[1];
    const float* fc1_w    = (const float*)d_in[3];
    const float* fc1_b    = (const float*)d_in[4];
    const float* gc_wih   = (const float*)d_in[5];
    const float* gc_whh   = (const float*)d_in[6];
    const float* gc_bih   = (const float*)d_in[7];
    const float* gc_bhh   = (const float*)d_in[8];
    const float* gp_wih   = (const float*)d_in[9];
    const float* gp_whh   = (const float*)d_in[10];
    const float* gp_bih   = (const float*)d_in[11];
    const float* gp_bhh   = (const float*)d_in[12];
    const float* gat_wq   = (const float*)d_in[13];
    const float* gat_wk   = (const float*)d_in[14];
    const float* gat_b    = (const float*)d_in[15];
    const float* mlp_w0   = (const float*)d_in[16];
    const float* mlp_b0   = (const float*)d_in[17];
    const float* mlp_w1   = (const float*)d_in[18];
    const float* mlp_b1   = (const float*)d_in[19];
    const float* mlp_w2   = (const float*)d_in[20];
    const float* mlp_b2   = (const float*)d_in[21];
    float* out = (float*)d_out;

    float* ws = (float*)d_ws;
    size_t off = 0;
    float* Hbuf = ws + off; off += (size_t)ROWS*HDIM;
    float* bufA = ws + off; off += (size_t)ROWS*G3;    // GHp
    float* bufB = ws + off; off += (size_t)ROWS*G3;    // GIc / x1
    float* bufC = ws + off; off += (size_t)ROWS*G3;    // GHc / x2
    float* Mbuf = ws + off; off += (size_t)ROWS*DD;
    h8* pwiQ = (h8*)(ws + off); off += (size_t)LL*NC4*G3*4;        // h8 = 4 floats
    h8* pwhQ = (h8*)(ws + off); off += (size_t)LL*NC4*G3*4;
    _Float16* gruF = (_Float16*)(ws + off); off += (size_t)12*G3*KP300/2;  // 12x [900][304] f16
    _Float16* fc1F = (_Float16*)(ws + off); off += (size_t)DD*EE/2;        // [300][1024]
    _Float16* mlp0F= (_Float16*)(ws + off); off += (size_t)DD*3728/2;      // [300][3728]
    _Float16* mlp1F= (_Float16*)(ws + off); off += (size_t)DD*KP300/2;     // [300][304]
    (void)ws_size; (void)in_sizes; (void)n_in; (void)out_size;

    // 1. weight prep
    {
        pack_w_q<<<dim3((NC4*G3+255)/256, LL), 256, 0, stream>>>(gp_wih, pwiQ);
        pack_w_q<<<dim3((NC4*G3+255)/256, LL), 256, 0, stream>>>(gp_whh, pwhQ);
        conv_gru_w<<<dim3((G3*KP300+255)/256, 12), 256, 0, stream>>>(gp_whh, gc_wih, gc_whh, gruF);
        convT<<<(DD*EE+255)/256, 256, 0, stream>>>(fc1_w, fc1F, EE, DD, EE);
        convT<<<(DD*3728+255)/256, 256, 0, stream>>>(mlp_w0, mlp0F, HDIM, DD, 3728);
        convT<<<(DD*KP300+255)/256, 256, 0, stream>>>(mlp_w1, mlp1F, DD, DD, KP300);
    }
    // 2. H0 = relu(features @ fc1_w + fc1_b) -> Hbuf col 0
    gemm_mfma<<<dim3(5,36),256,0,stream>>>(features, EE, fc1F, EE, fc1_b,
                                           Hbuf, HDIM, DD, EE, 1);
    // 3. features -> Hbuf cols [2700,3724)
    featcopy<<<ROWS,256,0,stream>>>(features, Hbuf);

    for (int l=0;l<LL;l++){
        int ccol  = (l==0)? 0 : 300 + (l-1)*600;
        int hcol  = l*300;
        int pcol  = 600 + l*600;
        int clcol = 300 + l*600;
        const h8* pwiQl = pwiQ + (size_t)l*NC4*G3;
        const h8* pwhQl = pwhQ + (size_t)l*NC4*G3;
        const _Float16* pwhF = gruF + (size_t)(l*3+0)*G3*KP300;
        const _Float16* cwiF = gruF + (size_t)(l*3+1)*G3*KP300;
        const _Float16* cwhF = gruF + (size_t)(l*3+2)*G3*KP300;

        // GHp = Hin @ pwh^T + pbh
        gemm_mfma<<<dim3(15,36),256,0,stream>>>(Hbuf+hcol, HDIM, pwhF, KP300,
                                                gp_bhh + l*G3, bufA, G3, G3, DD, 0);
        // fused: scan (blocks 0..47) + GIc GEMM (blocks 48..587) + local qdot
        scan_kernel<<<BB+GIC_TILES,1024,0,stream>>>(Hbuf, bufA, pwiQl, pwhQl,
                                          gp_bih + l*G3, gp_bhh + l*G3,
                                          gat_wk + l*DD, gat_wq + l*DD, gat_b, l,
                                          adj, Mbuf, ccol, hcol, pcol,
                                          cwiF, gc_bih + l*G3, bufB);
        // GHc = M @ cwh^T + cbh
        gemm_mfma<<<dim3(15,36),256,0,stream>>>(Mbuf, DD, cwhF, KP300,
                                                gc_bhh + l*G3, bufC, G3, G3, DD, 0);
        // CL = GRU-combine
        combine_c<<<ROWS,320,0,stream>>>(bufB, bufC, Mbuf, Hbuf, clcol);
    }

    // MLP
    gemm_mfma<<<dim3(5,36),256,0,stream>>>(Hbuf, HDIM, mlp0F, 3728, mlp_b0,
                                           bufB, DD, DD, HDIM, 1);
    gemm_mfma<<<dim3(5,36),256,0,stream>>>(bufB, DD, mlp1F, KP300, mlp_b1,
                                           bufC, DD, DD, DD, 1);
    logits_kernel<<<ROWS,64,0,stream>>>(bufC, mlp_w2, mlp_b2, out);
}

// Round 10
// 3194.353 us; speedup vs baseline: 1.8113x; 1.0375x over previous
//
#include <hip/hip_runtime.h>
#include <math.h>

#define BB 48
#define NN 96
#define EE 1024
#define DD 300
#define LL 4
#define G3 900          // 3*D
#define PP 150          // DD/2 f16 pairs
#define PP2 152         // padded pairs (38 chunks of 4)
#define NC4 38          // weight chunks of 4 pairs
#define HDIM 3724       // D*(2L+1)+E
#define ROWS (BB*NN)    // 4608
#define NEGI -1.0e30f
#define KP300 304       // 300 padded to mult-of-8
#define GIC_TILES 540   // 15 x 36 tiles for fused GIc GEMM

typedef _Float16 half2_t __attribute__((ext_vector_type(2)));
typedef _Float16 h8 __attribute__((ext_vector_type(8)));
typedef float f4 __attribute__((ext_vector_type(4)));

__device__ __forceinline__ float sigm(float x){ return 1.0f/(1.0f+expf(-x)); }

__device__ __forceinline__ void dot4(const h8 wv, const h8 mc,
                                     float& a0, float& a1, float& a2, float& a3)
{
    half2_t w0,w1,w2,w3,m0,m1,m2,m3;
    w0.x=wv[0]; w0.y=wv[1]; m0.x=mc[0]; m0.y=mc[1];
    w1.x=wv[2]; w1.y=wv[3]; m1.x=mc[2]; m1.y=mc[3];
    w2.x=wv[4]; w2.y=wv[5]; m2.x=mc[4]; m2.y=mc[5];
    w3.x=wv[6]; w3.y=wv[7]; m3.x=mc[6]; m3.y=mc[7];
    a0 = __builtin_amdgcn_fdot2(w0, m0, a0, false);
    a1 = __builtin_amdgcn_fdot2(w1, m1, a1, false);
    a2 = __builtin_amdgcn_fdot2(w2, m2, a2, false);
    a3 = __builtin_amdgcn_fdot2(w3, m3, a3, false);
}

// ---------------- pack W (L,900,300) -> coalesced h8 chunks (L,38,900) ----------------
__global__ __launch_bounds__(256) void pack_w_q(const float* __restrict__ src_all,
                                                h8* __restrict__ dst)
{
    int l = blockIdx.y;
    int idx = blockIdx.x*256 + threadIdx.x;
    if (idx >= NC4*G3) return;
    int c = idx / G3, gate = idx % G3;
    const float* src = src_all + (size_t)l*G3*DD + (size_t)gate*DD;
    h8 v;
    #pragma unroll
    for (int j=0;j<8;j++){
        int d = 8*c + j;
        v[j] = (d<DD) ? (_Float16)src[d] : (_Float16)0.f;
    }
    dst[(size_t)l*NC4*G3 + idx] = v;
}

// ---------------- GRU weights [900][300] fp32 -> [900][304] f16 (zero-padded) ----------------
__global__ __launch_bounds__(256) void conv_gru_w(const float* __restrict__ gp_whh,
                                                  const float* __restrict__ gc_wih,
                                                  const float* __restrict__ gc_whh,
                                                  _Float16* __restrict__ outp)
{
    int z = blockIdx.y; int l = z/3, wsel = z%3;
    const float* src = (wsel==0?gp_whh:wsel==1?gc_wih:gc_whh) + (size_t)l*G3*DD;
    _Float16* dst = outp + (size_t)z*G3*KP300;
    int idx = blockIdx.x*256 + threadIdx.x;
    if (idx >= G3*KP300) return;
    int n = idx/KP300, k = idx%KP300;
    dst[idx] = (k<DD) ? (_Float16)src[(size_t)n*DD+k] : (_Float16)0.f;
}

// ---------------- transpose-convert [K][N] fp32 -> [N][Kpad] f16 ----------------
__global__ __launch_bounds__(256) void convT(const float* __restrict__ src,
                                             _Float16* __restrict__ dst,
                                             int K, int N, int Kpad)
{
    int idx = blockIdx.x*256 + threadIdx.x;
    if (idx >= N*Kpad) return;
    int n = idx/Kpad, k = idx%Kpad;
    dst[idx] = (k<K) ? (_Float16)src[(size_t)k*N + n] : (_Float16)0.f;
}

// ---------------- MFMA f16 GEMM tile body (device fn, 256 active threads) ----------------
__device__ __forceinline__ void gemm_tile(
    int m0, int n0, int tid,
    const float* __restrict__ A, int lda,
    const _Float16* __restrict__ B, int Kpad,
    const float* __restrict__ bias,
    float* __restrict__ C, int ldc,
    int N, int K, int relu)
{
    constexpr int KPS=40;
    __shared__ _Float16 As[128][KPS];
    __shared__ _Float16 Bs[64][KPS];
    int w = tid>>6, lane = tid&63;
    int wy = w>>1, wx = w&1;
    int lm = lane&15, q = lane>>4;

    f4 acc[4][2];
    #pragma unroll
    for (int a=0;a<4;a++)
        #pragma unroll
        for (int b=0;b<2;b++)
            #pragma unroll
            for (int r=0;r<4;r++) acc[a][b][r]=0.f;

    int am = tid>>1, akg = (tid&1)*16;
    int bn = tid>>2, bkg = (tid&3)*8;
    const float* arow = A + (size_t)(m0+am)*lda;

    for (int k0=0; k0<K; k0+=32){
        {
            __align__(16) _Float16 av[16];
            #pragma unroll
            for (int u=0;u<16;u+=4){
                int k = k0 + akg + u;
                float x0,x1,x2,x3;
                if (k+4 <= K){
                    float4 v = *(const float4*)(arow + k);
                    x0=v.x;x1=v.y;x2=v.z;x3=v.w;
                } else {
                    x0 = (k  <K)? arow[k  ]:0.f;
                    x1 = (k+1<K)? arow[k+1]:0.f;
                    x2 = (k+2<K)? arow[k+2]:0.f;
                    x3 = (k+3<K)? arow[k+3]:0.f;
                }
                av[u]=(_Float16)x0; av[u+1]=(_Float16)x1;
                av[u+2]=(_Float16)x2; av[u+3]=(_Float16)x3;
            }
            *(h8*)&As[am][akg]   = *(h8*)&av[0];
            *(h8*)&As[am][akg+8] = *(h8*)&av[8];
        }
        {
            int gk = k0 + bkg;
            h8 bv;
            #pragma unroll
            for (int j=0;j<8;j++) bv[j]=(_Float16)0.f;
            if (n0+bn < N && gk < Kpad)
                bv = *(const h8*)(B + (size_t)(n0+bn)*Kpad + gk);
            *(h8*)&Bs[bn][bkg] = bv;
        }
        __syncthreads();
        h8 af[4], bf[2];
        #pragma unroll
        for (int mb=0; mb<4; mb++) af[mb] = *(h8*)&As[wy*64+mb*16+lm][q*8];
        #pragma unroll
        for (int nb=0; nb<2; nb++) bf[nb] = *(h8*)&Bs[wx*32+nb*16+lm][q*8];
        #pragma unroll
        for (int mb=0; mb<4; mb++)
            #pragma unroll
            for (int nb=0; nb<2; nb++)
                acc[mb][nb] = __builtin_amdgcn_mfma_f32_16x16x32_f16(af[mb], bf[nb], acc[mb][nb], 0,0,0);
        __syncthreads();
    }
    #pragma unroll
    for (int mb=0; mb<4; mb++){
        int r0 = m0 + wy*64 + mb*16 + q*4;
        #pragma unroll
        for (int nb=0; nb<2; nb++){
            int c = n0 + wx*32 + nb*16 + lm;
            if (c < N){
                float bb = bias[c];
                #pragma unroll
                for (int reg=0; reg<4; reg++){
                    float v = acc[mb][nb][reg] + bb;
                    if (relu) v = fmaxf(v, 0.f);
                    C[(size_t)(r0+reg)*ldc + c] = v;
                }
            }
        }
    }
}

// ---------------- standalone MFMA GEMM kernel ----------------
__global__ __launch_bounds__(256) void gemm_mfma(
    const float* __restrict__ A, int lda,
    const _Float16* __restrict__ B, int Kpad,
    const float* __restrict__ bias,
    float* __restrict__ C, int ldc,
    int N, int K, int relu)
{
    gemm_tile(blockIdx.y*128, blockIdx.x*64, threadIdx.x,
              A, lda, B, Kpad, bias, C, ldc, N, K, relu);
}

// ---------------- copy features into last 1024 cols of Hbuf ----------------
__global__ void featcopy(const float* __restrict__ f, float* __restrict__ H)
{
    size_t row = blockIdx.x;
    int t = threadIdx.x;
    float4 v = *(const float4*)(f + row*EE + t*4);
    *(float4*)(H + row*HDIM + 2700 + t*4) = v;
}

// ---------------- fused scan + GIc GEMM ----------------
// blocks 0..47: sequential p-scan. blocks 48..587: GIc GEMM tiles.
// Phase-D: 12 weight chunks RESIDENT in named registers (48 VGPRs, loaded once;
// launch_bounds(1024,4) -> 128-VGPR budget; no arrays -> no dynamic-index spill),
// remaining 26 chunks streamed coalesced from L2.
__global__ __launch_bounds__(1024, 4) void scan_kernel(
    float* __restrict__ Hbuf,
    const float* __restrict__ GHp,
    const h8* __restrict__ pwiQ,          // (38,900) h8 chunks of pwi
    const h8* __restrict__ pwhQ,          // (38,900) h8 chunks of pwh (init)
    const float* __restrict__ pbi,
    const float* __restrict__ pbh,
    const float* __restrict__ wk,
    const float* __restrict__ wq,
    const float* __restrict__ gat_b, int lidx,
    const float* __restrict__ adj,
    float* __restrict__ Mbuf,
    int ccol, int hcol, int pcol,
    const _Float16* __restrict__ cwiF,
    const float* __restrict__ cbi,
    float* __restrict__ GIc)
{
    // ---- GEMM blocks ----
    if (blockIdx.x >= BB){
        if (threadIdx.x < 256){
            int bid = blockIdx.x - BB;
            int n0 = (bid % 15)*64, m0 = (bid / 15)*128;
            gemm_tile(m0, n0, threadIdx.x, Hbuf + ccol, HDIM, cwiF, KP300,
                      cbi, GIc, G3, G3, DD, 0);
        }
        return;
    }

    int b = blockIdx.x;
    int t = threadIdx.x;

    __shared__ __align__(16) half2_t P_h2[NN][PP];   // 57600 B
    __shared__ __align__(16) float g_s[G3];
    __shared__ __align__(16) float Mpart[3][DD];
    __shared__ __align__(16) half2_t M_h2[PP2];
    __shared__ __align__(16) float e_s[NN];
    __shared__ __align__(16) float pk_s[NN];
    __shared__ __align__(16) float pw_s[DD];
    __shared__ __align__(16) float adj_s[NN*NN];
    __shared__ __align__(16) float qd_s[NN];
    __shared__ __align__(16) float ghp_s[G3];
    __shared__ __align__(16) float hv_s[DD];

    size_t rowbase = (size_t)b*NN;

    // ---- one-time: 12 resident weight chunks (named regs) + per-thread constants
    h8 wr0,wr1,wr2,wr3,wr4,wr5,wr6,wr7,wr8,wr9,wr10,wr11;
    float pbi_r = 0.f;
    if (t < G3){
        const h8* W = pwiQ + t;
        wr0 = W[0];        wr1 = W[(size_t)1*G3];  wr2 = W[(size_t)2*G3];
        wr3 = W[(size_t)3*G3];  wr4 = W[(size_t)4*G3];  wr5 = W[(size_t)5*G3];
        wr6 = W[(size_t)6*G3];  wr7 = W[(size_t)7*G3];  wr8 = W[(size_t)8*G3];
        wr9 = W[(size_t)9*G3];  wr10 = W[(size_t)10*G3]; wr11 = W[(size_t)11*G3];
        pbi_r = pbi[t];
    }
    float2 wk_r = make_float2(0.f,0.f);
    if (t < PP) wk_r = *(const float2*)&wk[2*t];

    // ---- init phase 1: adj staging + local qdot + Cin0 -> M
    for (int k=t; k<NN*NN; k+=1024) adj_s[k] = adj[rowbase*NN + k];
    {
        int w = t>>6, lane = t&63;
        float gb = gat_b[lidx];
        for (int r = w; r < NN; r += 16){
            const float* x = Hbuf + (rowbase + r)*HDIM + ccol;
            float s = 0.f;
            for (int d=lane; d<DD; d+=64) s += x[d]*wq[d];
            #pragma unroll
            for (int o=32;o>0;o>>=1) s += __shfl_xor(s,o);
            if (lane==0) qd_s[r] = s + gb;
        }
    }
    if (t < PP){
        float2 c2 = *(const float2*)&Hbuf[rowbase*HDIM + ccol + 2*t];
        Mpart[0][2*t] = c2.x; Mpart[0][2*t+1] = c2.y;
        half2_t mh; mh.x = (_Float16)c2.x; mh.y = (_Float16)c2.y;
        M_h2[t] = mh;
    } else if (t < PP2){
        half2_t z; z.x=(_Float16)0.f; z.y=(_Float16)0.f;
        M_h2[t] = z;
    }
    __syncthreads();
    // ---- init phase 2: gh0 = Cin0 @ pwh^T + pbh
    if (t < G3){
        const h8* W = pwhQ + t;
        float a0=0.f, a1=0.f, a2=0.f, a3=0.f;
        #pragma unroll 4
        for (int c=0;c<NC4;c++){
            h8 wv = W[(size_t)c*G3];
            h8 mc = *(h8*)&M_h2[4*c];
            dot4(wv, mc, a0,a1,a2,a3);
        }
        g_s[t] = pbh[t] + (a0+a2) + (a1+a3);
    }
    __syncthreads();
    // ---- init phase 3: p0 = GRU(x=0, h=Cin0); M[b,0]=0
    if (t < PP){
        int d0 = 2*t, d1 = 2*t+1;
        float r0  = sigm(pbi[d0]      + g_s[d0]);
        float z0  = sigm(pbi[DD+d0]   + g_s[DD+d0]);
        float n0  = tanhf(pbi[2*DD+d0] + r0*g_s[2*DD+d0]);
        float p0  = (1.f-z0)*n0 + z0*Mpart[0][d0];
        float r1  = sigm(pbi[d1]      + g_s[d1]);
        float z1  = sigm(pbi[DD+d1]   + g_s[DD+d1]);
        float n1  = tanhf(pbi[2*DD+d1] + r1*g_s[2*DD+d1]);
        float p1  = (1.f-z1)*n1 + z1*Mpart[0][d1];
        *(float2*)&Hbuf[rowbase*HDIM + pcol + d0] = make_float2(p0,p1);
        half2_t ph; ph.x = (_Float16)p0; ph.y = (_Float16)p1;
        P_h2[0][t] = ph;
        pw_s[d0] = p0*wk_r.x;
        pw_s[d1] = p1*wk_r.y;
        *(float2*)&Mbuf[rowbase*DD + d0] = make_float2(0.f,0.f);
    }
    __syncthreads();

    for (int i=1;i<NN;i++){
        size_t row = rowbase + i;
        // ---- AB (wave 0): pk reduce + logits + softmax
        if (t < 64){
            float s = 0.f;
            for (int c=t;c<DD;c+=64) s += pw_s[c];
            #pragma unroll
            for (int o=32;o>0;o>>=1) s += __shfl_xor(s,o);
            if (t==0) pk_s[i-1] = s;
            float q = qd_s[i];
            float a0 = NEGI, a1 = NEGI;
            if (t < i){
                if (adj_s[i*NN+t] != 0.f) a0 = q + ((t==i-1)? s : pk_s[t]);
            }
            int j1 = 64+t;
            if (t < 32 && j1 < i){
                if (adj_s[i*NN+j1] != 0.f) a1 = q + ((j1==i-1)? s : pk_s[j1]);
            }
            float m = fmaxf(a0,a1);
            #pragma unroll
            for (int o=32;o>0;o>>=1) m = fmaxf(m, __shfl_xor(m,o));
            float e0 = expf(a0-m);
            float e1 = (t<32)? expf(a1-m) : 0.f;
            float ss = e0+e1;
            #pragma unroll
            for (int o=32;o>0;o>>=1) ss += __shfl_xor(ss,o);
            float inv = 1.f/ss;
            e_s[t] = e0*inv;
            if (t<32) e_s[64+t] = e1*inv;
        }
        __syncthreads();
        // ---- C (t<450): 3-way j-split weighted sum; prefetchers (t>=512)
        if (t < 450){
            int g = t/150, dp = t%150;
            int cnt = (i+2)/3;
            int j0 = g*cnt; int j1 = j0+cnt; if (j1 > i) j1 = i;
            float m0=0.f, m1=0.f;
            for (int j=j0;j<j1;j++){
                float w = e_s[j];
                half2_t pv = P_h2[j][dp];
                m0 += w*(float)pv.x;
                m1 += w*(float)pv.y;
            }
            *(float2*)&Mpart[g][2*dp] = make_float2(m0,m1);
        } else if (t >= 512){
            int k = t-512;
            #pragma unroll
            for (int it=0; it<2; it++){
                int idx = k + it*512;
                if (idx < 450){
                    *(float2*)&ghp_s[2*idx] = *(const float2*)&GHp[row*G3 + 2*idx];
                } else if (idx < 600){
                    int h = idx-450;
                    *(float2*)&hv_s[2*h] = *(const float2*)&Hbuf[row*HDIM + hcol + 2*h];
                }
            }
        }
        __syncthreads();
        // ---- Csum (t<150): combine partials, write Mbuf + f16 M
        if (t < PP){
            float m0 = Mpart[0][2*t] + Mpart[1][2*t] + Mpart[2][2*t];
            float m1 = Mpart[0][2*t+1] + Mpart[1][2*t+1] + Mpart[2][2*t+1];
            half2_t mh; mh.x = (_Float16)m0; mh.y = (_Float16)m1;
            M_h2[t] = mh;
            *(float2*)&Mbuf[row*DD + 2*t] = make_float2(m0,m1);
        }
        __syncthreads();
        // ---- D (t<900): g = M @ pwi^T + pbi; 12 resident + 26 streamed chunks
        if (t < G3){
            const h8* W = pwiQ + t;
            float a0=0.f, a1=0.f, a2=0.f, a3=0.f;
            dot4(wr0,  *(h8*)&M_h2[0],  a0,a1,a2,a3);
            dot4(wr1,  *(h8*)&M_h2[4],  a0,a1,a2,a3);
            dot4(wr2,  *(h8*)&M_h2[8],  a0,a1,a2,a3);
            dot4(wr3,  *(h8*)&M_h2[12], a0,a1,a2,a3);
            dot4(wr4,  *(h8*)&M_h2[16], a0,a1,a2,a3);
            dot4(wr5,  *(h8*)&M_h2[20], a0,a1,a2,a3);
            dot4(wr6,  *(h8*)&M_h2[24], a0,a1,a2,a3);
            dot4(wr7,  *(h8*)&M_h2[28], a0,a1,a2,a3);
            dot4(wr8,  *(h8*)&M_h2[32], a0,a1,a2,a3);
            dot4(wr9,  *(h8*)&M_h2[36], a0,a1,a2,a3);
            dot4(wr10, *(h8*)&M_h2[40], a0,a1,a2,a3);
            dot4(wr11, *(h8*)&M_h2[44], a0,a1,a2,a3);
            #pragma unroll 4
            for (int c=12;c<NC4;c++){
                h8 wv = W[(size_t)c*G3];
                h8 mc = *(h8*)&M_h2[4*c];
                dot4(wv, mc, a0,a1,a2,a3);
            }
            g_s[t] = pbi_r + (a0+a2) + (a1+a3);
        }
        __syncthreads();
        // ---- E (t<150): GRU combine (pure LDS), write P row + pw
        if (t < PP){
            int d0 = 2*t, d1 = 2*t+1;
            float2 hv = *(const float2*)&hv_s[d0];
            float r0  = sigm(g_s[d0]      + ghp_s[d0]);
            float z0  = sigm(g_s[DD+d0]   + ghp_s[DD+d0]);
            float n0  = tanhf(g_s[2*DD+d0] + r0*ghp_s[2*DD+d0]);
            float p0  = (1.f-z0)*n0 + z0*hv.x;
            float r1  = sigm(g_s[d1]      + ghp_s[d1]);
            float z1  = sigm(g_s[DD+d1]   + ghp_s[DD+d1]);
            float n1  = tanhf(g_s[2*DD+d1] + r1*ghp_s[2*DD+d1]);
            float p1  = (1.f-z1)*n1 + z1*hv.y;
            *(float2*)&Hbuf[row*HDIM + pcol + d0] = make_float2(p0,p1);
            half2_t ph; ph.x = (_Float16)p0; ph.y = (_Float16)p1;
            P_h2[i][t] = ph;
            pw_s[d0] = p0*wk_r.x;
            pw_s[d1] = p1*wk_r.y;
        }
        __syncthreads();
    }
}

// ---------------- c-side elementwise combine ----------------
__global__ __launch_bounds__(320) void combine_c(
    const float* __restrict__ GIc, const float* __restrict__ GHc,
    const float* __restrict__ Mbuf, float* __restrict__ Hbuf, int clcol)
{
    size_t row = blockIdx.x;
    int d = threadIdx.x;
    if (d < DD){
        float ir = GIc[row*G3+d], iz = GIc[row*G3+DD+d], inn = GIc[row*G3+2*DD+d];
        float hr = GHc[row*G3+d], hz = GHc[row*G3+DD+d], hn  = GHc[row*G3+2*DD+d];
        float r  = sigm(ir+hr);
        float z  = sigm(iz+hz);
        float nn = tanhf(inn + r*hn);
        float h  = Mbuf[row*DD+d];
        Hbuf[row*HDIM + clcol + d] = (1.f-z)*nn + z*h;
    }
}

// ---------------- logits: out = x2 @ w2 + b2 (N=7) ----------------
__global__ __launch_bounds__(64) void logits_kernel(
    const float* __restrict__ x2, const float* __restrict__ w2,
    const float* __restrict__ b2, float* __restrict__ out)
{
    size_t row = blockIdx.x;
    int lane = threadIdx.x;
    float acc[7]={0,0,0,0,0,0,0};
    for (int d=lane; d<DD; d+=64){
        float x = x2[row*DD+d];
        #pragma unroll
        for (int c=0;c<7;c++) acc[c] += x*w2[d*7+c];
    }
    #pragma unroll
    for (int c=0;c<7;c++){
        float s = acc[c];
        #pragma unroll
        for (int o=32;o>0;o>>=1) s += __shfl_down(s,o);
        if (lane==0) out[row*7+c] = s + b2[c];
    }
}

extern "C" void kernel_launch(void* const* d_in, const int* in_sizes, int n_in,
                              void* d_out, int out_size, void* d_ws, size_t ws_size,
                              hipStream_t stream)
{
    const float* features = (const float*)d_in[0];
    const float* adj      = (const float*)d_in[1];
    const float* fc1_w    = (const float*)d_in[3];
    const float* fc1_b    = (const float*)d_in[4];
    const float* gc_wih   = (const float*)d_in[5];
    const float* gc_whh   = (const float*)d_in[6];
    const float* gc_bih   = (const float*)d_in[7];
    const float* gc_bhh   = (const float*)d_in[8];
    const float* gp_wih   = (const float*)d_in[9];
    const float* gp_whh   = (const float*)d_in[10];
    const float* gp_bih   = (const float*)d_in[11];
    const float* gp_bhh   = (const float*)d_in[12];
    const float* gat_wq   = (const float*)d_in[13];
    const float* gat_wk   = (const float*)d_in[14];
    const float* gat_b    = (const float*)d_in[15];
    const float* mlp_w0   = (const float*)d_in[16];
    const float* mlp_b0   = (const float*)d_in[17];
    const float* mlp_w1   = (const float*)d_in[18];
    const float* mlp_b1   = (const float*)d_in[19];
    const float* mlp_w2   = (const float*)d_in[20];
    const float* mlp_b2   = (const float*)d_in[21];
    float* out = (float*)d_out;

    float* ws = (float*)d_ws;
    size_t off = 0;
    float* Hbuf = ws + off; off += (size_t)ROWS*HDIM;
    float* bufA = ws + off; off += (size_t)ROWS*G3;    // GHp
    float* bufB = ws + off; off += (size_t)ROWS*G3;    // GIc / x1
    float* bufC = ws + off; off += (size_t)ROWS*G3;    // GHc / x2
    float* Mbuf = ws + off; off += (size_t)ROWS*DD;
    h8* pwiQ = (h8*)(ws + off); off += (size_t)LL*NC4*G3*4;
    h8* pwhQ = (h8*)(ws + off); off += (size_t)LL*NC4*G3*4;
    _Float16* gruF = (_Float16*)(ws + off); off += (size_t)12*G3*KP300/2;
    _Float16* fc1F = (_Float16*)(ws + off); off += (size_t)DD*EE/2;
    _Float16* mlp0F= (_Float16*)(ws + off); off += (size_t)DD*3728/2;
    _Float16* mlp1F= (_Float16*)(ws + off); off += (size_t)DD*KP300/2;
    (void)ws_size; (void)in_sizes; (void)n_in; (void)out_size;

    // 1. weight prep
    {
        pack_w_q<<<dim3((NC4*G3+255)/256, LL), 256, 0, stream>>>(gp_wih, pwiQ);
        pack_w_q<<<dim3((NC4*G3+255)/256, LL), 256, 0, stream>>>(gp_whh, pwhQ);
        conv_gru_w<<<dim3((G3*KP300+255)/256, 12), 256, 0, stream>>>(gp_whh, gc_wih, gc_whh, gruF);
        convT<<<(DD*EE+255)/256, 256, 0, stream>>>(fc1_w, fc1F, EE, DD, EE);
        convT<<<(DD*3728+255)/256, 256, 0, stream>>>(mlp_w0, mlp0F, HDIM, DD, 3728);
        convT<<<(DD*KP300+255)/256, 256, 0, stream>>>(mlp_w1, mlp1F, DD, DD, KP300);
    }
    // 2. H0 = relu(features @ fc1_w + fc1_b) -> Hbuf col 0
    gemm_mfma<<<dim3(5,36),256,0,stream>>>(features, EE, fc1F, EE, fc1_b,
                                           Hbuf, HDIM, DD, EE, 1);
    // 3. features -> Hbuf cols [2700,3724)
    featcopy<<<ROWS,256,0,stream>>>(features, Hbuf);

    for (int l=0;l<LL;l++){
        int ccol  = (l==0)? 0 : 300 + (l-1)*600;
        int hcol  = l*300;
        int pcol  = 600 + l*600;
        int clcol = 300 + l*600;
        const h8* pwiQl = pwiQ + (size_t)l*NC4*G3;
        const h8* pwhQl = pwhQ + (size_t)l*NC4*G3;
        const _Float16* pwhF = gruF + (size_t)(l*3+0)*G3*KP300;
        const _Float16* cwiF = gruF + (size_t)(l*3+1)*G3*KP300;
        const _Float16* cwhF = gruF + (size_t)(l*3+2)*G3*KP300;

        // GHp = Hin @ pwh^T + pbh
        gemm_mfma<<<dim3(15,36),256,0,stream>>>(Hbuf+hcol, HDIM, pwhF, KP300,
                                                gp_bhh + l*G3, bufA, G3, G3, DD, 0);
        // fused: scan (blocks 0..47) + GIc GEMM (blocks 48..587)
        scan_kernel<<<BB+GIC_TILES,1024,0,stream>>>(Hbuf, bufA, pwiQl, pwhQl,
                                          gp_bih + l*G3, gp_bhh + l*G3,
                                          gat_wk + l*DD, gat_wq + l*DD, gat_b, l,
                                          adj, Mbuf, ccol, hcol, pcol,
                                          cwiF, gc_bih + l*G3, bufB);
        // GHc = M @ cwh^T + cbh
        gemm_mfma<<<dim3(15,36),256,0,stream>>>(Mbuf, DD, cwhF, KP300,
                                                gc_bhh + l*G3, bufC, G3, G3, DD, 0);
        // CL = GRU-combine
        combine_c<<<ROWS,320,0,stream>>>(bufB, bufC, Mbuf, Hbuf, clcol);
    }

    // MLP
    gemm_mfma<<<dim3(5,36),256,0,stream>>>(Hbuf, HDIM, mlp0F, 3728, mlp_b0,
                                           bufB, DD, DD, HDIM, 1);
    gemm_mfma<<<dim3(5,36),256,0,stream>>>(bufB, DD, mlp1F, KP300, mlp_b1,
                                           bufC, DD, DD, DD, 1);
    logits_kernel<<<ROWS,64,0,stream>>>(bufC, mlp_w2, mlp_b2, out);
}